// Round 1
// baseline (865.064 us; speedup 1.0000x reference)
//
#include <hip/hip_runtime.h>
#include <hip/hip_bf16.h>
#include <math.h>

using bf16 = __hip_bfloat16;
typedef __attribute__((ext_vector_type(8))) short s8v;   // 8 x bf16 raw (4 VGPRs)
typedef __attribute__((ext_vector_type(4))) float f32x4;

#define B_  4
#define S_  2048
#define D_  1024
#define E_  1536
#define M_  (B_*S_)     // 8192 tokens
#define BE_ (B_*E_)     // 6144 sequences
#define NCH 16          // scan chunks
#define CHS (S_/NCH)    // 128 steps per chunk

__device__ __forceinline__ float b2f(bf16 h) { return __bfloat162float(h); }
__device__ __forceinline__ bf16  f2b(float f) { return __float2bfloat16(f); }

struct __align__(8)  bh4 { bf16 h[4]; };

__device__ __forceinline__ void gld16(const void* g, void* l) {
  __builtin_amdgcn_global_load_lds((const __attribute__((address_space(1))) void*)g,
                                   (__attribute__((address_space(3))) void*)l, 16, 0, 0);
}

// ---------------- fp32 -> bf16 conversion ----------------
__global__ __launch_bounds__(256) void cvt_k(const float* __restrict__ s,
                                             bf16* __restrict__ d, int n)
{
  int i = (blockIdx.x * 256 + threadIdx.x) * 4;
  if (i < n) {
    float4 v = *(const float4*)(s + i);
    bh4 o;
    o.h[0] = f2b(v.x); o.h[1] = f2b(v.y); o.h[2] = f2b(v.z); o.h[3] = f2b(v.w);
    *(bh4*)(d + i) = o;
  }
}

// ---------------- depthwise causal conv (K=4), fp32 in -> bf16 out ----------------
__global__ __launch_bounds__(256) void dwconv_k(const float* __restrict__ x,
                                                const float* __restrict__ w,
                                                const float* __restrict__ bias,
                                                bf16* __restrict__ out)
{
  int m = blockIdx.x;          // b*S + s
  int s = m & (S_ - 1);
  int d = threadIdx.x * 4;
  float wf[4][4];
#pragma unroll
  for (int i = 0; i < 4; ++i) {
    float4 wr = *(const float4*)(w + (d + i) * 4);
    wf[i][0] = wr.x; wf[i][1] = wr.y; wf[i][2] = wr.z; wf[i][3] = wr.w;
  }
  float4 bb = *(const float4*)(bias + d);
  float acc[4] = {bb.x, bb.y, bb.z, bb.w};
#pragma unroll
  for (int k = 0; k < 4; ++k) {
    if (s - 3 + k >= 0) {
      float4 xv = *(const float4*)(x + (size_t)(m - 3 + k) * D_ + d);
      acc[0] += xv.x * wf[0][k];
      acc[1] += xv.y * wf[1][k];
      acc[2] += xv.z * wf[2][k];
      acc[3] += xv.w * wf[3][k];
    }
  }
  bh4 ov;
#pragma unroll
  for (int i = 0; i < 4; ++i) ov.h[i] = f2b(acc[i]);
  *(bh4*)(out + (size_t)m * D_ + d) = ov;
}

// ======== GEMM 128x128 (legacy, kept for N=1024 cases): C=A*B^T, swizzled LDS ========
// EPI: 0 outH=bf16(v+bias+resid_f32) | 1 dual raw store col<1536->outH else outH2 (N=3072)
//      2 RMW outH=bf16(gh(v)*sigmoid(outH_raw)) | 3 outH=bf16(v+resid_f32)
//      4 outH=bf16(gelu(v+bias)) | 5 outF=v+bias (fp32 final)
template<int EPI>
__global__ __launch_bounds__(256) void gemm_ab(const bf16* __restrict__ A, int lda,
                                               const bf16* __restrict__ Bb, int ldb,
                                               const float* __restrict__ bias,
                                               const float* __restrict__ resid,
                                               bf16* outH, bf16* outH2, float* outF,
                                               int M, int N, int K)
{
  __shared__ __align__(16) bf16 lsA[128 * 64];
  __shared__ __align__(16) bf16 lsB[128 * 64];
  const int tid  = threadIdx.x;
  const int lane = tid & 63;
  const int wave = tid >> 6;
  const int m0 = blockIdx.y * 128, n0 = blockIdx.x * 128;
  const int wm = (wave >> 1) * 64, wn = (wave & 1) * 64;
  const int r = lane & 15, q = lane >> 4;
  const int sw = r & 7;
  f32x4 acc[4][4] = {};

  for (int k0 = 0; k0 < K; k0 += 64) {
#pragma unroll
    for (int i = 0; i < 4; ++i) {
      int c = i * 256 + tid;                   // LDS chunk id 0..1023
      int row = c >> 3, cc = (c & 7) ^ (row & 7);
      gld16(A  + (size_t)(m0 + row) * lda + k0 + cc * 8, (char*)lsA + c * 16);
      gld16(Bb + (size_t)(n0 + row) * ldb + k0 + cc * 8, (char*)lsB + c * 16);
    }
    __syncthreads();
#pragma unroll
    for (int kk = 0; kk < 64; kk += 32) {
      const int j = (kk >> 3) + q;
      s8v af[4], bfr[4];
#pragma unroll
      for (int t = 0; t < 4; ++t) {
        af[t]  = *(const s8v*)((char*)lsA + (((wm + t * 16 + r) << 3) + (j ^ sw)) * 16);
        bfr[t] = *(const s8v*)((char*)lsB + (((wn + t * 16 + r) << 3) + (j ^ sw)) * 16);
      }
#pragma unroll
      for (int mi = 0; mi < 4; ++mi)
#pragma unroll
        for (int ni = 0; ni < 4; ++ni)
          acc[mi][ni] = __builtin_amdgcn_mfma_f32_16x16x32_bf16(af[mi], bfr[ni], acc[mi][ni], 0, 0, 0);
    }
    __syncthreads();
  }

#pragma unroll
  for (int mi = 0; mi < 4; ++mi) {
#pragma unroll
    for (int j = 0; j < 4; ++j) {
      int row = m0 + wm + mi * 16 + q * 4 + j;
#pragma unroll
      for (int ni = 0; ni < 4; ++ni) {
        int col = n0 + wn + ni * 16 + r;
        size_t idx = (size_t)row * N + col;
        float v = acc[mi][ni][j];
        if constexpr (EPI == 0) {
          outH[idx] = f2b(v + bias[col] + resid[idx]);
        } else if constexpr (EPI == 1) {
          if (col < 1536) outH [(size_t)row * 1536 + col]        = f2b(v);
          else            outH2[(size_t)row * 1536 + col - 1536] = f2b(v);
        } else if constexpr (EPI == 2) {
          float gh = (v >= 0.f) ? (v + 0.5f) : (1.f / (1.f + expf(-v)));
          float iv = 1.f / (1.f + expf(-b2f(outH[idx])));
          outH[idx] = f2b(gh * iv);
        } else if constexpr (EPI == 3) {
          outH[idx] = f2b(v + resid[idx]);
        } else if constexpr (EPI == 4) {
          float u = v + bias[col];
          outH[idx] = f2b(0.5f * u * (1.f + erff(u * 0.70710678118f)));
        } else {
          outF[idx] = v + bias[col];
        }
      }
    }
  }
}

// ======== GEMM 256x256, 8-wave, 8-phase schedule with counted vmcnt (T2+T3+T4+T5) ========
// BK=64, LDS 128 KiB (2 dbuf x (A 32K + B 32K)), 1 block/CU, 8 waves as 2Mx4N,
// wave tile 128x64 -> acc[8][4] f32x4. Per K-tile: 4 MFMA phases (16 mfma each),
// staging of tile t+1 split into 4 steps issued one-per-phase:
//   S1=B rows 0-127, S2=B rows 128-255, S3=A rows {0-63,128-191}, S4=A rows {64-127,192-255}
// Sync: vmcnt(2)+bar at tile boundary (S1..S3(t) landed: full B + first A rows);
//       vmcnt(4)+bar mid-tile (S4(t) landed: second A rows). Never vmcnt(0) in loop.
// LDS swizzle: chunk slot s of row holds global col-group s^(row&7) (verified 0-conflict).
__device__ __forceinline__ void mfma_ph(f32x4 (*ac)[4], const s8v af[2][2], const s8v bf[4][2]) {
  __builtin_amdgcn_s_setprio(1);
#pragma unroll
  for (int kc = 0; kc < 2; ++kc)
#pragma unroll
    for (int mm = 0; mm < 2; ++mm)
#pragma unroll
      for (int n = 0; n < 4; ++n)
        ac[mm][n] = __builtin_amdgcn_mfma_f32_16x16x32_bf16(af[mm][kc], bf[n][kc], ac[mm][n], 0, 0, 0);
  __builtin_amdgcn_s_setprio(0);
}

template<int EPI>
__global__ __launch_bounds__(512, 2) void gemm8p(const bf16* __restrict__ A, int lda,
                                                 const bf16* __restrict__ Bb, int ldb,
                                                 const float* __restrict__ bias,
                                                 const float* __restrict__ resid,
                                                 bf16* outH, bf16* outH2, float* outF,
                                                 int M, int N, int K)
{
  __shared__ __align__(16) bf16 lsA[2][256 * 64];
  __shared__ __align__(16) bf16 lsB[2][256 * 64];
  const int tid  = threadIdx.x;
  const int lane = tid & 63;
  const int wave = tid >> 6;
  const int q = lane >> 4, r = lane & 15;
  const int wm = (wave >> 2) * 128;          // 2 waves in M
  const int wn = (wave & 3) * 64;            // 4 waves in N
  const int s0 = q ^ (r & 7);
  const int s0b  = s0 << 4;
  const int s0b4 = (s0 ^ 4) << 4;
  const int m0 = blockIdx.y * 256, n0 = blockIdx.x * 256;
  const int NT = K >> 6;

  f32x4 acc[8][4] = {};
  s8v af[2][2], bf4[4][2];

  // stage one 16KB half (1024 chunks, 2 gld16/thread). Addresses are loop-invariant
  // except tn*64 -> compiler hoists the per-thread offsets.
  auto stB = [&](int h, int tn, int nb) {
#pragma unroll
    for (int i = 0; i < 2; ++i) {
      int c  = (i << 9) + tid;
      int rw = (h << 7) + (c >> 3);
      int cc = (c & 7) ^ ((c >> 3) & 7);
      gld16(Bb + (unsigned)((n0 + rw) * ldb + (tn << 6) + (cc << 3)),
            (char*)lsB[nb] + (((h << 10) + c) << 4));
    }
  };
  auto stA = [&](int h, int tn, int nb) {
#pragma unroll
    for (int i = 0; i < 2; ++i) {
      int c   = (i << 9) + tid;
      int sub = c >> 3;
      int rw  = (sub & 63) + ((sub >> 6) << 7) + (h << 6);
      int cc  = (c & 7) ^ (sub & 7);
      gld16(A + (unsigned)((m0 + rw) * lda + (tn << 6) + (cc << 3)),
            (char*)lsA[nb] + (((rw << 3) + (c & 7)) << 4));
    }
  };

  // prologue: tile 0 -> buf 0 (issue order S1,S2,S3,S4; 8 loads/thread outstanding)
  stB(0, 0, 0); stB(1, 0, 0); stA(0, 0, 0); stA(1, 0, 0);

  for (int t = 0; t < NT; ++t) {
    const int cb = t & 1, nb = cb ^ 1;
    const int tn = (t + 1 < NT) ? t + 1 : t;   // clamped prefetch keeps vmcnt literals valid
    const char* lsAc = (const char*)lsA[cb];
    const char* lsBc = (const char*)lsB[cb];

    // ---- tile boundary: S1..S3(t) landed (all B + A rows {0-63,128-191}) ----
    asm volatile("s_waitcnt vmcnt(2)" ::: "memory");
    __builtin_amdgcn_s_barrier();

    // P0: all B-frags + A-frags m0,m1 ; issue S1(t+1)
    {
      const char* bb_ = lsBc + ((wn + r) << 7);
#pragma unroll
      for (int n = 0; n < 4; ++n) {
        bf4[n][0] = *(const s8v*)(bb_ + n * 2048 + s0b);
        bf4[n][1] = *(const s8v*)(bb_ + n * 2048 + s0b4);
      }
      const char* ab_ = lsAc + ((wm + r) << 7);
      af[0][0] = *(const s8v*)(ab_ + s0b);
      af[0][1] = *(const s8v*)(ab_ + s0b4);
      af[1][0] = *(const s8v*)(ab_ + 2048 + s0b);
      af[1][1] = *(const s8v*)(ab_ + 2048 + s0b4);
    }
    stB(0, tn, nb);
    __builtin_amdgcn_s_barrier();
    asm volatile("s_waitcnt lgkmcnt(0)" ::: "memory");
    mfma_ph(&acc[0], af, bf4);
    __builtin_amdgcn_s_barrier();

    // P1: A-frags m2,m3 ; issue S2(t+1)
    {
      const char* ab_ = lsAc + ((wm + 32 + r) << 7);
      af[0][0] = *(const s8v*)(ab_ + s0b);
      af[0][1] = *(const s8v*)(ab_ + s0b4);
      af[1][0] = *(const s8v*)(ab_ + 2048 + s0b);
      af[1][1] = *(const s8v*)(ab_ + 2048 + s0b4);
    }
    stB(1, tn, nb);
    __builtin_amdgcn_s_barrier();
    asm volatile("s_waitcnt lgkmcnt(0)" ::: "memory");
    mfma_ph(&acc[2], af, bf4);
    // ---- mid-tile: S4(t) landed (A rows {64-127,192-255}) ----
    asm volatile("s_waitcnt vmcnt(4)" ::: "memory");
    __builtin_amdgcn_s_barrier();

    // P2: A-frags m4,m5 ; issue S3(t+1)
    {
      const char* ab_ = lsAc + ((wm + 64 + r) << 7);
      af[0][0] = *(const s8v*)(ab_ + s0b);
      af[0][1] = *(const s8v*)(ab_ + s0b4);
      af[1][0] = *(const s8v*)(ab_ + 2048 + s0b);
      af[1][1] = *(const s8v*)(ab_ + 2048 + s0b4);
    }
    stA(0, tn, nb);
    __builtin_amdgcn_s_barrier();
    asm volatile("s_waitcnt lgkmcnt(0)" ::: "memory");
    mfma_ph(&acc[4], af, bf4);
    __builtin_amdgcn_s_barrier();

    // P3: A-frags m6,m7 ; issue S4(t+1)
    {
      const char* ab_ = lsAc + ((wm + 96 + r) << 7);
      af[0][0] = *(const s8v*)(ab_ + s0b);
      af[0][1] = *(const s8v*)(ab_ + s0b4);
      af[1][0] = *(const s8v*)(ab_ + 2048 + s0b);
      af[1][1] = *(const s8v*)(ab_ + 2048 + s0b4);
    }
    stA(1, tn, nb);
    __builtin_amdgcn_s_barrier();
    asm volatile("s_waitcnt lgkmcnt(0)" ::: "memory");
    mfma_ph(&acc[6], af, bf4);
    __builtin_amdgcn_s_barrier();
  }
  // drain pending global_load_lds before epilogue/endpgm (LDS of exiting wg)
  asm volatile("s_waitcnt vmcnt(0)" ::: "memory");

#pragma unroll
  for (int mi = 0; mi < 8; ++mi) {
#pragma unroll
    for (int j = 0; j < 4; ++j) {
      int row = m0 + wm + mi * 16 + q * 4 + j;
#pragma unroll
      for (int ni = 0; ni < 4; ++ni) {
        int col = n0 + wn + ni * 16 + r;
        size_t idx = (size_t)row * N + col;
        float v = acc[mi][ni][j];
        if constexpr (EPI == 0) {
          outH[idx] = f2b(v + bias[col] + resid[idx]);
        } else if constexpr (EPI == 1) {
          if (col < 1536) outH [(size_t)row * 1536 + col]        = f2b(v);
          else            outH2[(size_t)row * 1536 + col - 1536] = f2b(v);
        } else if constexpr (EPI == 2) {
          float gh = (v >= 0.f) ? (v + 0.5f) : (1.f / (1.f + expf(-v)));
          float iv = 1.f / (1.f + expf(-b2f(outH[idx])));
          outH[idx] = f2b(gh * iv);
        } else if constexpr (EPI == 3) {
          outH[idx] = f2b(v + resid[idx]);
        } else if constexpr (EPI == 4) {
          float u = v + bias[col];
          outH[idx] = f2b(0.5f * u * (1.f + erff(u * 0.70710678118f)));
        } else {
          outF[idx] = v + bias[col];
        }
      }
    }
  }
}

// ---------------- LayerNorm over D=1024, bf16 in -> bf16 out ----------------
__global__ __launch_bounds__(256) void ln_k(const bf16* __restrict__ y,
                                            const float* __restrict__ g,
                                            const float* __restrict__ b,
                                            bf16* __restrict__ out)
{
  __shared__ float sm[8];
  int row = blockIdx.x;
  bh4 v4 = ((const bh4*)(y + (size_t)row * D_))[threadIdx.x];
  float v0 = b2f(v4.h[0]), v1 = b2f(v4.h[1]), v2 = b2f(v4.h[2]), v3 = b2f(v4.h[3]);
  float s = v0 + v1 + v2 + v3;
#pragma unroll
  for (int o = 32; o; o >>= 1) s += __shfl_down(s, o);
  int lane = threadIdx.x & 63, w = threadIdx.x >> 6;
  if (lane == 0) sm[w] = s;
  __syncthreads();
  float mu = (sm[0] + sm[1] + sm[2] + sm[3]) * (1.f / D_);
  float d0 = v0 - mu, d1 = v1 - mu, d2 = v2 - mu, d3 = v3 - mu;
  float qq = d0 * d0 + d1 * d1 + d2 * d2 + d3 * d3;
#pragma unroll
  for (int o = 32; o; o >>= 1) qq += __shfl_down(qq, o);
  if (lane == 0) sm[4 + w] = qq;
  __syncthreads();
  float var = (sm[4] + sm[5] + sm[6] + sm[7]) * (1.f / D_);
  float inv = rsqrtf(var + 1e-5f);
  int c = threadIdx.x * 4;
  float4 gv = *(const float4*)(g + c);
  float4 bv = *(const float4*)(b + c);
  bh4 ov;
  ov.h[0] = f2b(d0 * inv * gv.x + bv.x);
  ov.h[1] = f2b(d1 * inv * gv.y + bv.y);
  ov.h[2] = f2b(d2 * inv * gv.z + bv.z);
  ov.h[3] = f2b(d3 * inv * gv.w + bv.w);
  *(bh4*)(out + (size_t)row * D_ + c) = ov;
}

// ---------------- chunked linear-recurrence scan: h' = sigmoid(fpre)*h + g ----------------
__global__ __launch_bounds__(256) void scanA2_k(const bf16* __restrict__ fpre,
                                                const bf16* __restrict__ g,
                                                float* __restrict__ Fc, float* __restrict__ Gc)
{
  int gth = blockIdx.x * 256 + threadIdx.x;
  int c = gth / BE_, be = gth % BE_;
  int b = be / E_,  e = be % E_;
  size_t idx = (size_t)b * S_ * E_ + (size_t)c * CHS * E_ + e;
  float F = 1.f, G = 0.f;
  for (int sl = 0; sl < CHS; ++sl, idx += E_) {
    float fv = 1.f / (1.f + expf(-b2f(fpre[idx])));
    F *= fv;
    G = fv * G + b2f(g[idx]);
  }
  Fc[gth] = F; Gc[gth] = G;
}

__global__ __launch_bounds__(256) void scanB_k(const float* __restrict__ Fc,
                                               const float* __restrict__ Gc,
                                               float* __restrict__ hst)
{
  int be = blockIdx.x * 256 + threadIdx.x;
  float h = 0.5f;
#pragma unroll
  for (int c = 0; c < NCH; ++c) {
    hst[c * BE_ + be] = h;
    h = Fc[c * BE_ + be] * h + Gc[c * BE_ + be];
  }
}

__global__ __launch_bounds__(256) void scanC2_k(const bf16* __restrict__ fpre,
                                                bf16* g,
                                                const float* __restrict__ hst)
{
  int gth = blockIdx.x * 256 + threadIdx.x;
  int c = gth / BE_, be = gth % BE_;
  int b = be / E_,  e = be % E_;
  size_t idx = (size_t)b * S_ * E_ + (size_t)c * CHS * E_ + e;
  float h = hst[gth];
  for (int sl = 0; sl < CHS; ++sl, idx += E_) {
    float fv = 1.f / (1.f + expf(-b2f(fpre[idx])));
    h = fv * h + b2f(g[idx]);
    g[idx] = f2b(h);
  }
}

extern "C" void kernel_launch(void* const* d_in, const int* in_sizes, int n_in,
                              void* d_out, int out_size, void* d_ws, size_t ws_size,
                              hipStream_t stream)
{
  (void)in_sizes; (void)n_in; (void)out_size; (void)ws_size;
  const float* x      = (const float*)d_in[0];
  const float* cdw_w  = (const float*)d_in[1];
  const float* cdw_b  = (const float*)d_in[2];
  const float* cpw_w  = (const float*)d_in[3];
  const float* cpw_b  = (const float*)d_in[4];
  const float* ln1_g  = (const float*)d_in[5];
  const float* ln1_b  = (const float*)d_in[6];
  const float* w_f    = (const float*)d_in[7];
  const float* w_i    = (const float*)d_in[8];
  const float* w_h    = (const float*)d_in[9];
  const float* w_down = (const float*)d_in[10];
  const float* ln2_g  = (const float*)d_in[11];
  const float* ln2_b  = (const float*)d_in[12];
  const float* mlp_w1 = (const float*)d_in[13];
  const float* mlp_b1 = (const float*)d_in[14];
  const float* mlp_w2 = (const float*)d_in[15];
  const float* mlp_b2 = (const float*)d_in[16];
  char* ws = (char*)d_ws;
  float* outF = (float*)d_out;

  bf16* dw_buf = (bf16*)(ws + 0);
  bf16* xln    = (bf16*)(ws + 0);
  float* Fc    = (float*)(ws + 0);
  float* Gc    = (float*)(ws + 393216);
  float* hst   = (float*)(ws + 786432);
  bf16* yb     = (bf16*)(ws + 16777216);
  bf16* hmid   = (bf16*)(ws + 16777216);   // 8192x4096 bf16 = 64 MiB, ends at 80 MiB
  bf16* fpre   = (bf16*)(ws + 33554432);
  bf16* gvals  = (bf16*)(ws + 58720256);
  bf16* pwb    = (bf16*)(ws + 83886080);
  bf16* wfib   = (bf16*)(ws + 85983232);
  bf16* whb    = (bf16*)(ws + 92274688);
  bf16* wdb    = (bf16*)(ws + 95420416);
  bf16* w1b    = (bf16*)(ws + 98566144);
  bf16* w2b    = (bf16*)(ws + 106954752);

  cvt_k<<<(D_*D_)/1024,   256, 0, stream>>>(cpw_w,  pwb, D_*D_);
  cvt_k<<<(E_*D_)/1024,   256, 0, stream>>>(w_f,    wfib, E_*D_);
  cvt_k<<<(E_*D_)/1024,   256, 0, stream>>>(w_i,    wfib + E_*D_, E_*D_);
  cvt_k<<<(E_*D_)/1024,   256, 0, stream>>>(w_h,    whb, E_*D_);
  cvt_k<<<(D_*E_)/1024,   256, 0, stream>>>(w_down, wdb, D_*E_);
  cvt_k<<<(4*D_*D_)/1024, 256, 0, stream>>>(mlp_w1, w1b, 4*D_*D_);
  cvt_k<<<(4*D_*D_)/1024, 256, 0, stream>>>(mlp_w2, w2b, 4*D_*D_);

  dwconv_k<<<M_, 256, 0, stream>>>(x, cdw_w, cdw_b, dw_buf);
  gemm_ab<0><<<dim3(8, 64), 256, 0, stream>>>(dw_buf, D_, pwb, D_, cpw_b, x, yb, nullptr, nullptr, M_, D_, D_);
  ln_k<<<M_, 256, 0, stream>>>(yb, ln1_g, ln1_b, xln);
  // fused f+i raw pre-activations (N=3072), then h RMW: g = gh(v)*sigmoid(ipre)
  gemm8p<1><<<dim3(12, 32), 512, 0, stream>>>(xln, D_, wfib, D_, nullptr, nullptr, fpre, gvals, nullptr, M_, 3072, D_);
  gemm8p<2><<<dim3(6, 32),  512, 0, stream>>>(xln, D_, whb, D_, nullptr, nullptr, gvals, nullptr, nullptr, M_, E_, D_);
  scanA2_k<<<(BE_*NCH)/256, 256, 0, stream>>>(fpre, gvals, Fc, Gc);
  scanB_k<<<BE_/256, 256, 0, stream>>>(Fc, Gc, hst);
  scanC2_k<<<(BE_*NCH)/256, 256, 0, stream>>>(fpre, gvals, hst);
  gemm_ab<3><<<dim3(8, 64), 256, 0, stream>>>(gvals, E_, wdb, E_, nullptr, x, yb, nullptr, nullptr, M_, D_, E_);
  ln_k<<<M_, 256, 0, stream>>>(yb, ln2_g, ln2_b, xln);
  // fused MLP: one N=4096 GEMM -> hmid, one K=4096 GEMM -> d_out (fp32, single write)
  gemm8p<4><<<dim3(16, 32), 512, 0, stream>>>(xln, D_, w1b, D_, mlp_b1, nullptr, hmid, nullptr, nullptr, M_, 4*D_, D_);
  gemm_ab<5><<<dim3(8, 64), 256, 0, stream>>>(hmid, 4*D_, w2b, 4*D_, mlp_b2, nullptr, nullptr, nullptr, outF, M_, D_, 4*D_);
}

// Round 2
// 723.536 us; speedup vs baseline: 1.1956x; 1.1956x over previous
//
#include <hip/hip_runtime.h>
#include <hip/hip_bf16.h>
#include <math.h>

using bf16 = __hip_bfloat16;
typedef __attribute__((ext_vector_type(8))) short s8v;   // 8 x bf16 raw (4 VGPRs)
typedef __attribute__((ext_vector_type(4))) float f32x4;

#define B_  4
#define S_  2048
#define D_  1024
#define E_  1536
#define M_  (B_*S_)     // 8192 tokens
#define BE_ (B_*E_)     // 6144 sequences
#define NCH 16          // scan chunks
#define CHS (S_/NCH)    // 128 steps per chunk

__device__ __forceinline__ float b2f(bf16 h) { return __bfloat162float(h); }
__device__ __forceinline__ bf16  f2b(float f) { return __float2bfloat16(f); }

struct __align__(8)  bh4 { bf16 h[4]; };

__device__ __forceinline__ void gld16(const void* g, void* l) {
  __builtin_amdgcn_global_load_lds((const __attribute__((address_space(1))) void*)g,
                                   (__attribute__((address_space(3))) void*)l, 16, 0, 0);
}

// ---------------- fused fp32 -> bf16 conversion of all 7 weight tensors ----------------
// dst is one contiguous bf16 region: pw | w_f | w_i | w_h | w_down | mlp_w1 | mlp_w2
__global__ __launch_bounds__(256) void cvt7_k(const float* __restrict__ s0,
                                              const float* __restrict__ s1,
                                              const float* __restrict__ s2,
                                              const float* __restrict__ s3,
                                              const float* __restrict__ s4,
                                              const float* __restrict__ s5,
                                              const float* __restrict__ s6,
                                              bf16* __restrict__ d)
{
  size_t i = ((size_t)blockIdx.x * 256 + threadIdx.x) * 4;
  const float* s; size_t off;
  if (i < 4194304) {
    if (i < 1048576)      { s = s0; off = 0; }
    else if (i < 2621440) { s = s1; off = 1048576; }
    else                  { s = s2; off = 2621440; }
  } else if (i < 7340032) {
    if (i < 5767168)      { s = s3; off = 4194304; }
    else                  { s = s4; off = 5767168; }
  } else {
    if (i < 11534336)     { s = s5; off = 7340032; }
    else                  { s = s6; off = 11534336; }
  }
  float4 v = *(const float4*)(s + (i - off));
  bh4 o;
  o.h[0] = f2b(v.x); o.h[1] = f2b(v.y); o.h[2] = f2b(v.z); o.h[3] = f2b(v.w);
  *(bh4*)(d + i) = o;
}

// ---------------- depthwise causal conv (K=4), fp32 in -> bf16 out ----------------
__global__ __launch_bounds__(256) void dwconv_k(const float* __restrict__ x,
                                                const float* __restrict__ w,
                                                const float* __restrict__ bias,
                                                bf16* __restrict__ out)
{
  int m = blockIdx.x;          // b*S + s
  int s = m & (S_ - 1);
  int d = threadIdx.x * 4;
  float wf[4][4];
#pragma unroll
  for (int i = 0; i < 4; ++i) {
    float4 wr = *(const float4*)(w + (d + i) * 4);
    wf[i][0] = wr.x; wf[i][1] = wr.y; wf[i][2] = wr.z; wf[i][3] = wr.w;
  }
  float4 bb = *(const float4*)(bias + d);
  float acc[4] = {bb.x, bb.y, bb.z, bb.w};
#pragma unroll
  for (int k = 0; k < 4; ++k) {
    if (s - 3 + k >= 0) {
      float4 xv = *(const float4*)(x + (size_t)(m - 3 + k) * D_ + d);
      acc[0] += xv.x * wf[0][k];
      acc[1] += xv.y * wf[1][k];
      acc[2] += xv.z * wf[2][k];
      acc[3] += xv.w * wf[3][k];
    }
  }
  bh4 ov;
#pragma unroll
  for (int i = 0; i < 4; ++i) ov.h[i] = f2b(acc[i]);
  *(bh4*)(out + (size_t)m * D_ + d) = ov;
}

// ======== GEMM 128x128: C(M,N)=A(M,K,lda)*B^T(N,K,ldb), bf16, dbuf LDS + counted vmcnt ========
// LDS tile 128x64 bf16 per matrix, double-buffered (64 KiB total, 2 blocks/CU).
// Row r chunk slot s holds global column-group s^(r&7) -> conflict-free ds_read_b128 (verified).
// Stage units per thread/tile: U1=B full (4 gld16), U2=A rows{0-31,64-95} (2), U3=A rows{32-63,96-127} (2).
// Schedule per tile t (buffers cb=t&1, nb=cb^1):
//   vmcnt(2)+bar  [U1,U2(t) landed; U3(t)+nothing else in flight]
//   issue U1,U2(t+1)->nb ; ds_read B-all + A-half0 ; 16 MFMA (acc[0..1][*])
//   vmcnt(6)+bar  [U3(t) landed]
//   issue U3(t+1)->nb ; ds_read A-half1 ; 16 MFMA (acc[2..3][*])
// Every wait targets loads issued ~a full tile earlier; vmcnt never drained to 0 in-loop.
// Race-free: writes to buf[b] are issued only after a barrier that postdates all reads of
// buf[b]'s previous tile (each ds_read is consumed by an MFMA before its wave's barrier).
// EPI: 0 outH=bf16(v+bias+resid_f32) | 1 dual raw store col<1536->outH else outH2 (N=3072)
//      2 RMW outH=bf16(gh(v)*sigmoid(outH_raw)) | 3 outH=bf16(v+resid_f32)
//      4 outH=bf16(gelu(v+bias)) | 5 outF=v+bias (fp32 final)
template<int EPI>
__global__ __launch_bounds__(256, 2) void gemm_ab(const bf16* __restrict__ A, int lda,
                                                  const bf16* __restrict__ Bb, int ldb,
                                                  const float* __restrict__ bias,
                                                  const float* __restrict__ resid,
                                                  bf16* outH, bf16* outH2, float* outF,
                                                  int M, int N, int K)
{
  __shared__ __align__(16) bf16 lsA[2][128 * 64];
  __shared__ __align__(16) bf16 lsB[2][128 * 64];
  const int tid  = threadIdx.x;
  const int lane = tid & 63;
  const int wave = tid >> 6;
  const int m0 = blockIdx.y * 128, n0 = blockIdx.x * 128;
  const int wm = (wave >> 1) * 64, wn = (wave & 1) * 64;
  const int r = lane & 15, q = lane >> 4;
  const int sw = r & 7;
  f32x4 acc[4][4] = {};

  // U1: full B tile (4 gld16/thread)
  auto stB = [&](int tn, int nb) {
#pragma unroll
    for (int i = 0; i < 4; ++i) {
      int c = i * 256 + tid;                   // 0..1023
      int row = c >> 3, cc = (c & 7) ^ (row & 7);
      gld16(Bb + (size_t)(n0 + row) * ldb + tn * 64 + cc * 8, (char*)lsB[nb] + c * 16);
    }
  };
  // U2/U3: A half h -> rows {0-31,64-95} (h=0) / {32-63,96-127} (h=1), 2 gld16/thread
  auto stA = [&](int h, int tn, int nb) {
#pragma unroll
    for (int i = 0; i < 2; ++i) {
      int c = i * 256 + tid;                   // 0..511
      int sub = c >> 3;                        // 0..63
      int rw = (sub & 31) + ((sub >> 5) << 6) + h * 32;
      int cc = (c & 7) ^ (sub & 7);            // rw&7 == sub&7
      gld16(A + (size_t)(m0 + rw) * lda + tn * 64 + cc * 8,
            (char*)lsA[nb] + (((rw << 3) + (c & 7)) << 4));
    }
  };

  const int NT = K >> 6;
  // prologue: tile 0 -> buf 0 (issue order U1,U2,U3 => 8 loads/thread in flight)
  stB(0, 0); stA(0, 0, 0); stA(1, 0, 0);

  for (int t = 0; t < NT; ++t) {
    const int cb = t & 1, nb = cb ^ 1;
    const int tn = (t + 1 < NT) ? (t + 1) : t; // clamped prefetch keeps counts uniform
    const char* la = (const char*)lsA[cb];
    const char* lb = (const char*)lsB[cb];

    // ---- H0: U1,U2(t) landed for this wave; barrier makes it true block-wide ----
    asm volatile("s_waitcnt vmcnt(2)" ::: "memory");
    __builtin_amdgcn_s_barrier();
    stB(tn, nb); stA(0, tn, nb);               // in flight: U3(t)+U1,U2(t+1) = 8

    s8v bfr[4][2], af[2][2];
#pragma unroll
    for (int ni = 0; ni < 4; ++ni)
#pragma unroll
      for (int kc = 0; kc < 2; ++kc)
        bfr[ni][kc] = *(const s8v*)(lb + ((((wn + ni * 16 + r) << 3) + ((q + kc * 4) ^ sw)) << 4));
#pragma unroll
    for (int mi = 0; mi < 2; ++mi)
#pragma unroll
      for (int kc = 0; kc < 2; ++kc)
        af[mi][kc] = *(const s8v*)(la + ((((wm + mi * 16 + r) << 3) + ((q + kc * 4) ^ sw)) << 4));
    __builtin_amdgcn_s_setprio(1);
#pragma unroll
    for (int kc = 0; kc < 2; ++kc)
#pragma unroll
      for (int mi = 0; mi < 2; ++mi)
#pragma unroll
        for (int ni = 0; ni < 4; ++ni)
          acc[mi][ni] = __builtin_amdgcn_mfma_f32_16x16x32_bf16(af[mi][kc], bfr[ni][kc], acc[mi][ni], 0, 0, 0);
    __builtin_amdgcn_s_setprio(0);

    // ---- H1: U3(t) landed ----
    asm volatile("s_waitcnt vmcnt(6)" ::: "memory");
    __builtin_amdgcn_s_barrier();
    stA(1, tn, nb);                            // in flight: U1,U2,U3(t+1) = 8
#pragma unroll
    for (int mi = 0; mi < 2; ++mi)
#pragma unroll
      for (int kc = 0; kc < 2; ++kc)
        af[mi][kc] = *(const s8v*)(la + ((((wm + (mi + 2) * 16 + r) << 3) + ((q + kc * 4) ^ sw)) << 4));
    __builtin_amdgcn_s_setprio(1);
#pragma unroll
    for (int kc = 0; kc < 2; ++kc)
#pragma unroll
      for (int mi = 0; mi < 2; ++mi)
#pragma unroll
        for (int ni = 0; ni < 4; ++ni)
          acc[mi + 2][ni] = __builtin_amdgcn_mfma_f32_16x16x32_bf16(af[mi][kc], bfr[ni][kc], acc[mi + 2][ni], 0, 0, 0);
    __builtin_amdgcn_s_setprio(0);
  }
  // drain pending LDS-DMA before epilogue / wave exit
  asm volatile("s_waitcnt vmcnt(0)" ::: "memory");

#pragma unroll
  for (int mi = 0; mi < 4; ++mi) {
#pragma unroll
    for (int j = 0; j < 4; ++j) {
      int row = m0 + wm + mi * 16 + q * 4 + j;
#pragma unroll
      for (int ni = 0; ni < 4; ++ni) {
        int col = n0 + wn + ni * 16 + r;
        size_t idx = (size_t)row * N + col;
        float v = acc[mi][ni][j];
        if constexpr (EPI == 0) {
          outH[idx] = f2b(v + bias[col] + resid[idx]);
        } else if constexpr (EPI == 1) {
          if (col < 1536) outH [(size_t)row * 1536 + col]        = f2b(v);
          else            outH2[(size_t)row * 1536 + col - 1536] = f2b(v);
        } else if constexpr (EPI == 2) {
          float gh = (v >= 0.f) ? (v + 0.5f) : (1.f / (1.f + expf(-v)));
          float iv = 1.f / (1.f + expf(-b2f(outH[idx])));
          outH[idx] = f2b(gh * iv);
        } else if constexpr (EPI == 3) {
          outH[idx] = f2b(v + resid[idx]);
        } else if constexpr (EPI == 4) {
          float u = v + bias[col];
          outH[idx] = f2b(0.5f * u * (1.f + erff(u * 0.70710678118f)));
        } else {
          outF[idx] = v + bias[col];
        }
      }
    }
  }
}

// ---------------- LayerNorm over D=1024, bf16 in -> bf16 out ----------------
__global__ __launch_bounds__(256) void ln_k(const bf16* __restrict__ y,
                                            const float* __restrict__ g,
                                            const float* __restrict__ b,
                                            bf16* __restrict__ out)
{
  __shared__ float sm[8];
  int row = blockIdx.x;
  bh4 v4 = ((const bh4*)(y + (size_t)row * D_))[threadIdx.x];
  float v0 = b2f(v4.h[0]), v1 = b2f(v4.h[1]), v2 = b2f(v4.h[2]), v3 = b2f(v4.h[3]);
  float s = v0 + v1 + v2 + v3;
#pragma unroll
  for (int o = 32; o; o >>= 1) s += __shfl_down(s, o);
  int lane = threadIdx.x & 63, w = threadIdx.x >> 6;
  if (lane == 0) sm[w] = s;
  __syncthreads();
  float mu = (sm[0] + sm[1] + sm[2] + sm[3]) * (1.f / D_);
  float d0 = v0 - mu, d1 = v1 - mu, d2 = v2 - mu, d3 = v3 - mu;
  float qq = d0 * d0 + d1 * d1 + d2 * d2 + d3 * d3;
#pragma unroll
  for (int o = 32; o; o >>= 1) qq += __shfl_down(qq, o);
  if (lane == 0) sm[4 + w] = qq;
  __syncthreads();
  float var = (sm[4] + sm[5] + sm[6] + sm[7]) * (1.f / D_);
  float inv = rsqrtf(var + 1e-5f);
  int c = threadIdx.x * 4;
  float4 gv = *(const float4*)(g + c);
  float4 bv = *(const float4*)(b + c);
  bh4 ov;
  ov.h[0] = f2b(d0 * inv * gv.x + bv.x);
  ov.h[1] = f2b(d1 * inv * gv.y + bv.y);
  ov.h[2] = f2b(d2 * inv * gv.z + bv.z);
  ov.h[3] = f2b(d3 * inv * gv.w + bv.w);
  *(bh4*)(out + (size_t)row * D_ + c) = ov;
}

// ---------------- chunked linear-recurrence scan: h' = sigmoid(fpre)*h + g ----------------
__global__ __launch_bounds__(256) void scanA2_k(const bf16* __restrict__ fpre,
                                                const bf16* __restrict__ g,
                                                float* __restrict__ Fc, float* __restrict__ Gc)
{
  int gth = blockIdx.x * 256 + threadIdx.x;
  int c = gth / BE_, be = gth % BE_;
  int b = be / E_,  e = be % E_;
  size_t idx = (size_t)b * S_ * E_ + (size_t)c * CHS * E_ + e;
  float F = 1.f, G = 0.f;
  for (int sl = 0; sl < CHS; ++sl, idx += E_) {
    float fv = 1.f / (1.f + expf(-b2f(fpre[idx])));
    F *= fv;
    G = fv * G + b2f(g[idx]);
  }
  Fc[gth] = F; Gc[gth] = G;
}

__global__ __launch_bounds__(256) void scanB_k(const float* __restrict__ Fc,
                                               const float* __restrict__ Gc,
                                               float* __restrict__ hst)
{
  int be = blockIdx.x * 256 + threadIdx.x;
  float h = 0.5f;
#pragma unroll
  for (int c = 0; c < NCH; ++c) {
    hst[c * BE_ + be] = h;
    h = Fc[c * BE_ + be] * h + Gc[c * BE_ + be];
  }
}

__global__ __launch_bounds__(256) void scanC2_k(const bf16* __restrict__ fpre,
                                                bf16* g,
                                                const float* __restrict__ hst)
{
  int gth = blockIdx.x * 256 + threadIdx.x;
  int c = gth / BE_, be = gth % BE_;
  int b = be / E_,  e = be % E_;
  size_t idx = (size_t)b * S_ * E_ + (size_t)c * CHS * E_ + e;
  float h = hst[gth];
  for (int sl = 0; sl < CHS; ++sl, idx += E_) {
    float fv = 1.f / (1.f + expf(-b2f(fpre[idx])));
    h = fv * h + b2f(g[idx]);
    g[idx] = f2b(h);
  }
}

extern "C" void kernel_launch(void* const* d_in, const int* in_sizes, int n_in,
                              void* d_out, int out_size, void* d_ws, size_t ws_size,
                              hipStream_t stream)
{
  (void)in_sizes; (void)n_in; (void)out_size; (void)ws_size;
  const float* x      = (const float*)d_in[0];
  const float* cdw_w  = (const float*)d_in[1];
  const float* cdw_b  = (const float*)d_in[2];
  const float* cpw_w  = (const float*)d_in[3];
  const float* cpw_b  = (const float*)d_in[4];
  const float* ln1_g  = (const float*)d_in[5];
  const float* ln1_b  = (const float*)d_in[6];
  const float* w_f    = (const float*)d_in[7];
  const float* w_i    = (const float*)d_in[8];
  const float* w_h    = (const float*)d_in[9];
  const float* w_down = (const float*)d_in[10];
  const float* ln2_g  = (const float*)d_in[11];
  const float* ln2_b  = (const float*)d_in[12];
  const float* mlp_w1 = (const float*)d_in[13];
  const float* mlp_b1 = (const float*)d_in[14];
  const float* mlp_w2 = (const float*)d_in[15];
  const float* mlp_b2 = (const float*)d_in[16];
  char* ws = (char*)d_ws;
  float* outF = (float*)d_out;

  bf16* dw_buf = (bf16*)(ws + 0);
  bf16* xln    = (bf16*)(ws + 0);
  float* Fc    = (float*)(ws + 0);
  float* Gc    = (float*)(ws + 393216);
  float* hst   = (float*)(ws + 786432);
  bf16* yb     = (bf16*)(ws + 16777216);
  bf16* hmid   = (bf16*)(ws + 16777216);   // 8192x4096 bf16 = 64 MiB, ends at 80 MiB
  bf16* fpre   = (bf16*)(ws + 33554432);
  bf16* gvals  = (bf16*)(ws + 58720256);
  bf16* pwb    = (bf16*)(ws + 83886080);   // start of contiguous bf16 weight region
  bf16* wfib   = (bf16*)(ws + 85983232);
  bf16* whb    = (bf16*)(ws + 92274688);
  bf16* wdb    = (bf16*)(ws + 95420416);
  bf16* w1b    = (bf16*)(ws + 98566144);
  bf16* w2b    = (bf16*)(ws + 106954752);

  // one fused conversion: 15,728,640 elems -> contiguous [pwb .. w2b+4M)
  cvt7_k<<<15360, 256, 0, stream>>>(cpw_w, w_f, w_i, w_h, w_down, mlp_w1, mlp_w2, pwb);

  dwconv_k<<<M_, 256, 0, stream>>>(x, cdw_w, cdw_b, dw_buf);
  gemm_ab<0><<<dim3(8, 64), 256, 0, stream>>>(dw_buf, D_, pwb, D_, cpw_b, x, yb, nullptr, nullptr, M_, D_, D_);
  ln_k<<<M_, 256, 0, stream>>>(yb, ln1_g, ln1_b, xln);
  // fused f+i raw pre-activations (N=3072), then h RMW: g = gh(v)*sigmoid(ipre)
  gemm_ab<1><<<dim3(24, 64), 256, 0, stream>>>(xln, D_, wfib, D_, nullptr, nullptr, fpre, gvals, nullptr, M_, 3072, D_);
  gemm_ab<2><<<dim3(12, 64), 256, 0, stream>>>(xln, D_, whb, D_, nullptr, nullptr, gvals, nullptr, nullptr, M_, E_, D_);
  scanA2_k<<<(BE_*NCH)/256, 256, 0, stream>>>(fpre, gvals, Fc, Gc);
  scanB_k<<<BE_/256, 256, 0, stream>>>(Fc, Gc, hst);
  scanC2_k<<<(BE_*NCH)/256, 256, 0, stream>>>(fpre, gvals, hst);
  gemm_ab<3><<<dim3(8, 64), 256, 0, stream>>>(gvals, E_, wdb, E_, nullptr, x, yb, nullptr, nullptr, M_, D_, E_);
  ln_k<<<M_, 256, 0, stream>>>(yb, ln2_g, ln2_b, xln);
  // fused MLP: one N=4096 GEMM -> hmid, one K=4096 GEMM -> d_out (fp32, single write)
  gemm_ab<4><<<dim3(32, 64), 256, 0, stream>>>(xln, D_, w1b, D_, mlp_b1, nullptr, hmid, nullptr, nullptr, M_, 4*D_, D_);
  gemm_ab<5><<<dim3(8, 64), 256, 0, stream>>>(hmid, 4*D_, w2b, 4*D_, mlp_b2, nullptr, nullptr, nullptr, outF, M_, D_, 4*D_);
}

// Round 3
// 668.934 us; speedup vs baseline: 1.2932x; 1.0816x over previous
//
#include <hip/hip_runtime.h>
#include <hip/hip_bf16.h>
#include <math.h>

using bf16 = __hip_bfloat16;
typedef __attribute__((ext_vector_type(8))) short s8v;   // 8 x bf16 raw (4 VGPRs)
typedef __attribute__((ext_vector_type(4))) float f32x4;

#define B_  4
#define S_  2048
#define D_  1024
#define E_  1536
#define M_  (B_*S_)     // 8192 tokens
#define BE_ (B_*E_)     // 6144 sequences
#define NCH 16          // scan chunks
#define CHS (S_/NCH)    // 128 steps per chunk

__device__ __forceinline__ float b2f(bf16 h) { return __bfloat162float(h); }
__device__ __forceinline__ bf16  f2b(float f) { return __float2bfloat16(f); }

struct __align__(8)  bh4 { bf16 h[4]; };

__device__ __forceinline__ void gld16(const void* g, void* l) {
  __builtin_amdgcn_global_load_lds((const __attribute__((address_space(1))) void*)g,
                                   (__attribute__((address_space(3))) void*)l, 16, 0, 0);
}

// ---------------- fused fp32 -> bf16 conversion of all 7 weight tensors ----------------
// dst is one contiguous bf16 region: pw | w_f | w_i | w_h | w_down | mlp_w1 | mlp_w2
__global__ __launch_bounds__(256) void cvt7_k(const float* __restrict__ s0,
                                              const float* __restrict__ s1,
                                              const float* __restrict__ s2,
                                              const float* __restrict__ s3,
                                              const float* __restrict__ s4,
                                              const float* __restrict__ s5,
                                              const float* __restrict__ s6,
                                              bf16* __restrict__ d)
{
  size_t i = ((size_t)blockIdx.x * 256 + threadIdx.x) * 4;
  const float* s; size_t off;
  if (i < 4194304) {
    if (i < 1048576)      { s = s0; off = 0; }
    else if (i < 2621440) { s = s1; off = 1048576; }
    else                  { s = s2; off = 2621440; }
  } else if (i < 7340032) {
    if (i < 5767168)      { s = s3; off = 4194304; }
    else                  { s = s4; off = 5767168; }
  } else {
    if (i < 11534336)     { s = s5; off = 7340032; }
    else                  { s = s6; off = 11534336; }
  }
  float4 v = *(const float4*)(s + (i - off));
  bh4 o;
  o.h[0] = f2b(v.x); o.h[1] = f2b(v.y); o.h[2] = f2b(v.z); o.h[3] = f2b(v.w);
  *(bh4*)(d + i) = o;
}

// ---------------- depthwise causal conv (K=4), fp32 in -> bf16 out ----------------
__global__ __launch_bounds__(256) void dwconv_k(const float* __restrict__ x,
                                                const float* __restrict__ w,
                                                const float* __restrict__ bias,
                                                bf16* __restrict__ out)
{
  int m = blockIdx.x;          // b*S + s
  int s = m & (S_ - 1);
  int d = threadIdx.x * 4;
  float wf[4][4];
#pragma unroll
  for (int i = 0; i < 4; ++i) {
    float4 wr = *(const float4*)(w + (d + i) * 4);
    wf[i][0] = wr.x; wf[i][1] = wr.y; wf[i][2] = wr.z; wf[i][3] = wr.w;
  }
  float4 bb = *(const float4*)(bias + d);
  float acc[4] = {bb.x, bb.y, bb.z, bb.w};
#pragma unroll
  for (int k = 0; k < 4; ++k) {
    if (s - 3 + k >= 0) {
      float4 xv = *(const float4*)(x + (size_t)(m - 3 + k) * D_ + d);
      acc[0] += xv.x * wf[0][k];
      acc[1] += xv.y * wf[1][k];
      acc[2] += xv.z * wf[2][k];
      acc[3] += xv.w * wf[3][k];
    }
  }
  bh4 ov;
#pragma unroll
  for (int i = 0; i < 4; ++i) ov.h[i] = f2b(acc[i]);
  *(bh4*)(out + (size_t)m * D_ + d) = ov;
}

// ---------------- shared epilogue ----------------
template<int EPI>
__device__ __forceinline__ void epi_store(float v, int row, int col, int N,
                                          const float* __restrict__ bias,
                                          const float* __restrict__ resid,
                                          bf16* outH, bf16* outH2, float* outF)
{
  size_t idx = (size_t)row * N + col;
  if constexpr (EPI == 0) {
    outH[idx] = f2b(v + bias[col] + resid[idx]);
  } else if constexpr (EPI == 1) {
    if (col < 1536) outH [(size_t)row * 1536 + col]        = f2b(v);
    else            outH2[(size_t)row * 1536 + col - 1536] = f2b(v);
  } else if constexpr (EPI == 2) {
    float gh = (v >= 0.f) ? (v + 0.5f) : (1.f / (1.f + expf(-v)));
    float iv = 1.f / (1.f + expf(-b2f(outH[idx])));
    outH[idx] = f2b(gh * iv);
  } else if constexpr (EPI == 3) {
    outH[idx] = f2b(v + resid[idx]);
  } else if constexpr (EPI == 4) {
    float u = v + bias[col];
    outH[idx] = f2b(0.5f * u * (1.f + erff(u * 0.70710678118f)));
  } else {
    outF[idx] = v + bias[col];
  }
}

// ======== GEMM 128x128 (proven baseline): C(M,N)=A(M,K,lda)*B^T(N,K,ldb), bf16 ========
// Single-buffer LDS, stage-all -> syncthreads -> 32 MFMA -> syncthreads. TLP across
// resident blocks hides the vmcnt(0) drain (m114). XOR-swizzled LDS: row r chunk slot s
// holds global column-group s^(r&7) -> conflict-free ds_read_b128 (verified 0-conflict).
template<int EPI>
__global__ __launch_bounds__(256) void gemm_ab(const bf16* __restrict__ A, int lda,
                                               const bf16* __restrict__ Bb, int ldb,
                                               const float* __restrict__ bias,
                                               const float* __restrict__ resid,
                                               bf16* outH, bf16* outH2, float* outF,
                                               int M, int N, int K)
{
  __shared__ __align__(16) bf16 lsA[128 * 64];
  __shared__ __align__(16) bf16 lsB[128 * 64];
  const int tid  = threadIdx.x;
  const int lane = tid & 63;
  const int wave = tid >> 6;
  const int m0 = blockIdx.y * 128, n0 = blockIdx.x * 128;
  const int wm = (wave >> 1) * 64, wn = (wave & 1) * 64;
  const int r = lane & 15, q = lane >> 4;
  const int sw = r & 7;
  f32x4 acc[4][4] = {};

  for (int k0 = 0; k0 < K; k0 += 64) {
#pragma unroll
    for (int i = 0; i < 4; ++i) {
      int c = i * 256 + tid;                   // LDS chunk id 0..1023
      int row = c >> 3, cc = (c & 7) ^ (row & 7);
      gld16(A  + (size_t)(m0 + row) * lda + k0 + cc * 8, (char*)lsA + c * 16);
      gld16(Bb + (size_t)(n0 + row) * ldb + k0 + cc * 8, (char*)lsB + c * 16);
    }
    __syncthreads();
#pragma unroll
    for (int kk = 0; kk < 64; kk += 32) {
      const int j = (kk >> 3) + q;
      s8v af[4], bfr[4];
#pragma unroll
      for (int t = 0; t < 4; ++t) {
        af[t]  = *(const s8v*)((char*)lsA + (((wm + t * 16 + r) << 3) + (j ^ sw)) * 16);
        bfr[t] = *(const s8v*)((char*)lsB + (((wn + t * 16 + r) << 3) + (j ^ sw)) * 16);
      }
#pragma unroll
      for (int mi = 0; mi < 4; ++mi)
#pragma unroll
        for (int ni = 0; ni < 4; ++ni)
          acc[mi][ni] = __builtin_amdgcn_mfma_f32_16x16x32_bf16(af[mi], bfr[ni], acc[mi][ni], 0, 0, 0);
    }
    __syncthreads();
  }

#pragma unroll
  for (int mi = 0; mi < 4; ++mi)
#pragma unroll
    for (int j = 0; j < 4; ++j) {
      int row = m0 + wm + mi * 16 + q * 4 + j;
#pragma unroll
      for (int ni = 0; ni < 4; ++ni)
        epi_store<EPI>(acc[mi][ni][j], row, n0 + wn + ni * 16 + r, N, bias, resid, outH, outH2, outF);
    }
}

// ======== GEMM 128x256 (wide-N): same sync structure, 512 threads, 8 waves (2M x 4N) ========
// Per-wave output 64x64 (acc[4][4], identical register budget). Staged bytes per output
// elem 1.5B vs 2B; 6 gld16/thread vs 8. LDS 48KB; __launch_bounds__(512,4) caps VGPR at
// 128 -> 2 blocks/CU = 16 waves/CU. Fragment/swizzle/epilogue formulas identical to gemm_ab.
template<int EPI>
__global__ __launch_bounds__(512, 4) void gemm_wide(const bf16* __restrict__ A, int lda,
                                                    const bf16* __restrict__ Bb, int ldb,
                                                    const float* __restrict__ bias,
                                                    const float* __restrict__ resid,
                                                    bf16* outH, bf16* outH2, float* outF,
                                                    int M, int N, int K)
{
  __shared__ __align__(16) bf16 lsA[128 * 64];
  __shared__ __align__(16) bf16 lsB[256 * 64];
  const int tid  = threadIdx.x;                // 0..511
  const int lane = tid & 63;
  const int wave = tid >> 6;                   // 0..7
  const int m0 = blockIdx.y * 128, n0 = blockIdx.x * 256;
  const int wm = (wave >> 2) * 64;             // 0 / 64
  const int wn = (wave & 3) * 64;              // 0 / 64 / 128 / 192
  const int r = lane & 15, q = lane >> 4;
  const int sw = r & 7;
  f32x4 acc[4][4] = {};

  for (int k0 = 0; k0 < K; k0 += 64) {
    // stage A: 1024 chunks (128 rows x 8), 2 per thread
#pragma unroll
    for (int i = 0; i < 2; ++i) {
      int c = i * 512 + tid;                   // 0..1023
      int row = c >> 3, cc = (c & 7) ^ (row & 7);
      gld16(A + (size_t)(m0 + row) * lda + k0 + cc * 8, (char*)lsA + c * 16);
    }
    // stage B: 2048 chunks (256 rows x 8), 4 per thread
#pragma unroll
    for (int i = 0; i < 4; ++i) {
      int c = i * 512 + tid;                   // 0..2047
      int row = c >> 3, cc = (c & 7) ^ (row & 7);
      gld16(Bb + (size_t)(n0 + row) * ldb + k0 + cc * 8, (char*)lsB + c * 16);
    }
    __syncthreads();
#pragma unroll
    for (int kk = 0; kk < 64; kk += 32) {
      const int j = (kk >> 3) + q;
      s8v af[4], bfr[4];
#pragma unroll
      for (int t = 0; t < 4; ++t) {
        af[t]  = *(const s8v*)((char*)lsA + (((wm + t * 16 + r) << 3) + (j ^ sw)) * 16);
        bfr[t] = *(const s8v*)((char*)lsB + (((wn + t * 16 + r) << 3) + (j ^ sw)) * 16);
      }
#pragma unroll
      for (int mi = 0; mi < 4; ++mi)
#pragma unroll
        for (int ni = 0; ni < 4; ++ni)
          acc[mi][ni] = __builtin_amdgcn_mfma_f32_16x16x32_bf16(af[mi], bfr[ni], acc[mi][ni], 0, 0, 0);
    }
    __syncthreads();
  }

#pragma unroll
  for (int mi = 0; mi < 4; ++mi)
#pragma unroll
    for (int j = 0; j < 4; ++j) {
      int row = m0 + wm + mi * 16 + q * 4 + j;
#pragma unroll
      for (int ni = 0; ni < 4; ++ni)
        epi_store<EPI>(acc[mi][ni][j], row, n0 + wn + ni * 16 + r, N, bias, resid, outH, outH2, outF);
    }
}

// ---------------- LayerNorm over D=1024, bf16 in -> bf16 out ----------------
__global__ __launch_bounds__(256) void ln_k(const bf16* __restrict__ y,
                                            const float* __restrict__ g,
                                            const float* __restrict__ b,
                                            bf16* __restrict__ out)
{
  __shared__ float sm[8];
  int row = blockIdx.x;
  bh4 v4 = ((const bh4*)(y + (size_t)row * D_))[threadIdx.x];
  float v0 = b2f(v4.h[0]), v1 = b2f(v4.h[1]), v2 = b2f(v4.h[2]), v3 = b2f(v4.h[3]);
  float s = v0 + v1 + v2 + v3;
#pragma unroll
  for (int o = 32; o; o >>= 1) s += __shfl_down(s, o);
  int lane = threadIdx.x & 63, w = threadIdx.x >> 6;
  if (lane == 0) sm[w] = s;
  __syncthreads();
  float mu = (sm[0] + sm[1] + sm[2] + sm[3]) * (1.f / D_);
  float d0 = v0 - mu, d1 = v1 - mu, d2 = v2 - mu, d3 = v3 - mu;
  float qq = d0 * d0 + d1 * d1 + d2 * d2 + d3 * d3;
#pragma unroll
  for (int o = 32; o; o >>= 1) qq += __shfl_down(qq, o);
  if (lane == 0) sm[4 + w] = qq;
  __syncthreads();
  float var = (sm[4] + sm[5] + sm[6] + sm[7]) * (1.f / D_);
  float inv = rsqrtf(var + 1e-5f);
  int c = threadIdx.x * 4;
  float4 gv = *(const float4*)(g + c);
  float4 bv = *(const float4*)(b + c);
  bh4 ov;
  ov.h[0] = f2b(d0 * inv * gv.x + bv.x);
  ov.h[1] = f2b(d1 * inv * gv.y + bv.y);
  ov.h[2] = f2b(d2 * inv * gv.z + bv.z);
  ov.h[3] = f2b(d3 * inv * gv.w + bv.w);
  *(bh4*)(out + (size_t)row * D_ + c) = ov;
}

// ---------------- chunked linear-recurrence scan: h' = sigmoid(fpre)*h + g ----------------
__global__ __launch_bounds__(256) void scanA2_k(const bf16* __restrict__ fpre,
                                                const bf16* __restrict__ g,
                                                float* __restrict__ Fc, float* __restrict__ Gc)
{
  int gth = blockIdx.x * 256 + threadIdx.x;
  int c = gth / BE_, be = gth % BE_;
  int b = be / E_,  e = be % E_;
  size_t idx = (size_t)b * S_ * E_ + (size_t)c * CHS * E_ + e;
  float F = 1.f, G = 0.f;
  for (int sl = 0; sl < CHS; ++sl, idx += E_) {
    float fv = 1.f / (1.f + expf(-b2f(fpre[idx])));
    F *= fv;
    G = fv * G + b2f(g[idx]);
  }
  Fc[gth] = F; Gc[gth] = G;
}

__global__ __launch_bounds__(256) void scanB_k(const float* __restrict__ Fc,
                                               const float* __restrict__ Gc,
                                               float* __restrict__ hst)
{
  int be = blockIdx.x * 256 + threadIdx.x;
  float h = 0.5f;
#pragma unroll
  for (int c = 0; c < NCH; ++c) {
    hst[c * BE_ + be] = h;
    h = Fc[c * BE_ + be] * h + Gc[c * BE_ + be];
  }
}

__global__ __launch_bounds__(256) void scanC2_k(const bf16* __restrict__ fpre,
                                                bf16* g,
                                                const float* __restrict__ hst)
{
  int gth = blockIdx.x * 256 + threadIdx.x;
  int c = gth / BE_, be = gth % BE_;
  int b = be / E_,  e = be % E_;
  size_t idx = (size_t)b * S_ * E_ + (size_t)c * CHS * E_ + e;
  float h = hst[gth];
  for (int sl = 0; sl < CHS; ++sl, idx += E_) {
    float fv = 1.f / (1.f + expf(-b2f(fpre[idx])));
    h = fv * h + b2f(g[idx]);
    g[idx] = f2b(h);
  }
}

extern "C" void kernel_launch(void* const* d_in, const int* in_sizes, int n_in,
                              void* d_out, int out_size, void* d_ws, size_t ws_size,
                              hipStream_t stream)
{
  (void)in_sizes; (void)n_in; (void)out_size; (void)ws_size;
  const float* x      = (const float*)d_in[0];
  const float* cdw_w  = (const float*)d_in[1];
  const float* cdw_b  = (const float*)d_in[2];
  const float* cpw_w  = (const float*)d_in[3];
  const float* cpw_b  = (const float*)d_in[4];
  const float* ln1_g  = (const float*)d_in[5];
  const float* ln1_b  = (const float*)d_in[6];
  const float* w_f    = (const float*)d_in[7];
  const float* w_i    = (const float*)d_in[8];
  const float* w_h    = (const float*)d_in[9];
  const float* w_down = (const float*)d_in[10];
  const float* ln2_g  = (const float*)d_in[11];
  const float* ln2_b  = (const float*)d_in[12];
  const float* mlp_w1 = (const float*)d_in[13];
  const float* mlp_b1 = (const float*)d_in[14];
  const float* mlp_w2 = (const float*)d_in[15];
  const float* mlp_b2 = (const float*)d_in[16];
  char* ws = (char*)d_ws;
  float* outF = (float*)d_out;

  bf16* dw_buf = (bf16*)(ws + 0);
  bf16* xln    = (bf16*)(ws + 0);
  float* Fc    = (float*)(ws + 0);
  float* Gc    = (float*)(ws + 393216);
  float* hst   = (float*)(ws + 786432);
  bf16* yb     = (bf16*)(ws + 16777216);
  bf16* hmid   = (bf16*)(ws + 16777216);   // 8192x4096 bf16 = 64 MiB, ends at 80 MiB
  bf16* fpre   = (bf16*)(ws + 33554432);
  bf16* gvals  = (bf16*)(ws + 58720256);
  bf16* pwb    = (bf16*)(ws + 83886080);   // start of contiguous bf16 weight region
  bf16* wfib   = (bf16*)(ws + 85983232);
  bf16* whb    = (bf16*)(ws + 92274688);
  bf16* wdb    = (bf16*)(ws + 95420416);
  bf16* w1b    = (bf16*)(ws + 98566144);
  bf16* w2b    = (bf16*)(ws + 106954752);

  // one fused conversion: 15,728,640 elems -> contiguous [pwb .. w2b+4M)
  cvt7_k<<<15360, 256, 0, stream>>>(cpw_w, w_f, w_i, w_h, w_down, mlp_w1, mlp_w2, pwb);

  dwconv_k<<<M_, 256, 0, stream>>>(x, cdw_w, cdw_b, dw_buf);
  gemm_ab<0><<<dim3(8, 64), 256, 0, stream>>>(dw_buf, D_, pwb, D_, cpw_b, x, yb, nullptr, nullptr, M_, D_, D_);
  ln_k<<<M_, 256, 0, stream>>>(yb, ln1_g, ln1_b, xln);
  // fused f+i raw pre-activations (N=3072), then h RMW: g = gh(v)*sigmoid(ipre)
  gemm_wide<1><<<dim3(12, 64), 512, 0, stream>>>(xln, D_, wfib, D_, nullptr, nullptr, fpre, gvals, nullptr, M_, 3072, D_);
  gemm_wide<2><<<dim3(6, 64),  512, 0, stream>>>(xln, D_, whb, D_, nullptr, nullptr, gvals, nullptr, nullptr, M_, E_, D_);
  scanA2_k<<<(BE_*NCH)/256, 256, 0, stream>>>(fpre, gvals, Fc, Gc);
  scanB_k<<<BE_/256, 256, 0, stream>>>(Fc, Gc, hst);
  scanC2_k<<<(BE_*NCH)/256, 256, 0, stream>>>(fpre, gvals, hst);
  gemm_ab<3><<<dim3(8, 64), 256, 0, stream>>>(gvals, E_, wdb, E_, nullptr, x, yb, nullptr, nullptr, M_, D_, E_);
  ln_k<<<M_, 256, 0, stream>>>(yb, ln2_g, ln2_b, xln);
  // fused MLP: one N=4096 GEMM -> hmid, one K=4096 GEMM -> d_out (fp32, single write)
  gemm_wide<4><<<dim3(16, 64), 512, 0, stream>>>(xln, D_, w1b, D_, mlp_b1, nullptr, hmid, nullptr, nullptr, M_, 4*D_, D_);
  gemm_ab<5><<<dim3(8, 64), 256, 0, stream>>>(hmid, 4*D_, w2b, 4*D_, mlp_b2, nullptr, nullptr, nullptr, outF, M_, D_, 4*D_);
}

// Round 4
// 624.067 us; speedup vs baseline: 1.3862x; 1.0719x over previous
//
#include <hip/hip_runtime.h>
#include <hip/hip_bf16.h>
#include <math.h>

using bf16 = __hip_bfloat16;
typedef __attribute__((ext_vector_type(8))) short s8v;   // 8 x bf16 raw (4 VGPRs)
typedef __attribute__((ext_vector_type(4))) float f32x4;

#define B_  4
#define S_  2048
#define D_  1024
#define E_  1536
#define M_  (B_*S_)     // 8192 tokens
#define BE_ (B_*E_)     // 6144 sequences
#define NCH 128         // scan chunks (vec8 scan: 384 blocks, 16 steps/chunk)
#define CHS (S_/NCH)    // 16 steps per chunk
#define TS_ 16          // dwconv tokens per block

__device__ __forceinline__ float b2f(bf16 h) { return __bfloat162float(h); }
__device__ __forceinline__ bf16  f2b(float f) { return __float2bfloat16(f); }
__device__ __forceinline__ float su2f(short v) {        // raw bf16 bits -> f32 (exact)
  unsigned u = ((unsigned)(unsigned short)v) << 16;
  return __builtin_bit_cast(float, u);
}
__device__ __forceinline__ short f2bs(float f) { return __builtin_bit_cast(short, f2b(f)); }

struct __align__(8)  bh4 { bf16 h[4]; };
struct __align__(16) bh8 { bf16 h[8]; };

__device__ __forceinline__ void gld16(const void* g, void* l) {
  __builtin_amdgcn_global_load_lds((const __attribute__((address_space(1))) void*)g,
                                   (__attribute__((address_space(3))) void*)l, 16, 0, 0);
}

// ---------------- fused fp32 -> bf16 conversion of all 7 weight tensors ----------------
__global__ __launch_bounds__(256) void cvt7_k(const float* __restrict__ s0,
                                              const float* __restrict__ s1,
                                              const float* __restrict__ s2,
                                              const float* __restrict__ s3,
                                              const float* __restrict__ s4,
                                              const float* __restrict__ s5,
                                              const float* __restrict__ s6,
                                              bf16* __restrict__ d)
{
  size_t i = ((size_t)blockIdx.x * 256 + threadIdx.x) * 4;
  const float* s; size_t off;
  if (i < 4194304) {
    if (i < 1048576)      { s = s0; off = 0; }
    else if (i < 2621440) { s = s1; off = 1048576; }
    else                  { s = s2; off = 2621440; }
  } else if (i < 7340032) {
    if (i < 5767168)      { s = s3; off = 4194304; }
    else                  { s = s4; off = 5767168; }
  } else {
    if (i < 11534336)     { s = s5; off = 7340032; }
    else                  { s = s6; off = 11534336; }
  }
  float4 v = *(const float4*)(s + (i - off));
  bh4 o;
  o.h[0] = f2b(v.x); o.h[1] = f2b(v.y); o.h[2] = f2b(v.z); o.h[3] = f2b(v.w);
  *(bh4*)(d + i) = o;
}

// ---------------- depthwise causal conv (K=4), 16 tokens/block, fp32 in -> bf16 out ----------------
// Block handles tokens m0..m0+15 for all D. Each thread owns 4 channels, loads 19 rows
// of float4 once (read amp 1.19x vs 4x), computes 16 outputs. 2048%16==0 -> no batch straddle.
__global__ __launch_bounds__(256) void dwconv_k(const float* __restrict__ x,
                                                const float* __restrict__ w,
                                                const float* __restrict__ bias,
                                                bf16* __restrict__ out)
{
  int m0 = blockIdx.x * TS_;
  int s0 = m0 & (S_ - 1);
  int d = threadIdx.x * 4;
  float wf[4][4];
#pragma unroll
  for (int i = 0; i < 4; ++i) {
    float4 wr = *(const float4*)(w + (d + i) * 4);
    wf[i][0] = wr.x; wf[i][1] = wr.y; wf[i][2] = wr.z; wf[i][3] = wr.w;
  }
  float4 bb = *(const float4*)(bias + d);

  float4 xr[TS_ + 3];
#pragma unroll
  for (int j = 0; j < TS_ + 3; ++j) {
    int srow = s0 - 3 + j;
    if (srow >= 0) xr[j] = *(const float4*)(x + (size_t)(m0 - 3 + j) * D_ + d);
    else           xr[j] = make_float4(0.f, 0.f, 0.f, 0.f);
  }
#pragma unroll
  for (int t = 0; t < TS_; ++t) {
    float a0 = bb.x, a1 = bb.y, a2 = bb.z, a3 = bb.w;
#pragma unroll
    for (int k = 0; k < 4; ++k) {
      float4 xv = xr[t + k];
      a0 += xv.x * wf[0][k];
      a1 += xv.y * wf[1][k];
      a2 += xv.z * wf[2][k];
      a3 += xv.w * wf[3][k];
    }
    bh4 ov;
    ov.h[0] = f2b(a0); ov.h[1] = f2b(a1); ov.h[2] = f2b(a2); ov.h[3] = f2b(a3);
    *(bh4*)(out + (size_t)(m0 + t) * D_ + d) = ov;
  }
}

// ---------------- shared epilogue ----------------
template<int EPI>
__device__ __forceinline__ void epi_store(float v, int row, int col, int N,
                                          const float* __restrict__ bias,
                                          const float* __restrict__ resid,
                                          bf16* outH, bf16* outH2, float* outF)
{
  size_t idx = (size_t)row * N + col;
  if constexpr (EPI == 0) {
    outH[idx] = f2b(v + bias[col] + resid[idx]);
  } else if constexpr (EPI == 1) {
    if (col < 1536) outH [(size_t)row * 1536 + col]        = f2b(v);
    else            outH2[(size_t)row * 1536 + col - 1536] = f2b(v);
  } else if constexpr (EPI == 2) {
    float gh = (v >= 0.f) ? (v + 0.5f) : (1.f / (1.f + expf(-v)));
    float iv = 1.f / (1.f + expf(-b2f(outH[idx])));
    outH[idx] = f2b(gh * iv);
  } else if constexpr (EPI == 3) {
    outH[idx] = f2b(v + resid[idx]);
  } else if constexpr (EPI == 4) {
    float u = v + bias[col];
    outH[idx] = f2b(0.5f * u * (1.f + erff(u * 0.70710678118f)));
  } else {
    outF[idx] = v + bias[col];
  }
}

// ======== GEMM 128x128 (proven): C(M,N)=A(M,K,lda)*B^T(N,K,ldb), bf16, swizzled LDS ========
// Single-buffer LDS, stage-all -> syncthreads -> 32 MFMA -> syncthreads. TLP across
// resident blocks hides the drain (m114). Row r chunk slot s holds col-group s^(r&7):
// conflict-free ds_read_b128 (measured 0 bank conflicts).
template<int EPI>
__global__ __launch_bounds__(256) void gemm_ab(const bf16* __restrict__ A, int lda,
                                               const bf16* __restrict__ Bb, int ldb,
                                               const float* __restrict__ bias,
                                               const float* __restrict__ resid,
                                               bf16* outH, bf16* outH2, float* outF,
                                               int M, int N, int K)
{
  __shared__ __align__(16) bf16 lsA[128 * 64];
  __shared__ __align__(16) bf16 lsB[128 * 64];
  const int tid  = threadIdx.x;
  const int lane = tid & 63;
  const int wave = tid >> 6;
  const int m0 = blockIdx.y * 128, n0 = blockIdx.x * 128;
  const int wm = (wave >> 1) * 64, wn = (wave & 1) * 64;
  const int r = lane & 15, q = lane >> 4;
  const int sw = r & 7;
  f32x4 acc[4][4] = {};

  for (int k0 = 0; k0 < K; k0 += 64) {
#pragma unroll
    for (int i = 0; i < 4; ++i) {
      int c = i * 256 + tid;                   // LDS chunk id 0..1023
      int row = c >> 3, cc = (c & 7) ^ (row & 7);
      gld16(A  + (size_t)(m0 + row) * lda + k0 + cc * 8, (char*)lsA + c * 16);
      gld16(Bb + (size_t)(n0 + row) * ldb + k0 + cc * 8, (char*)lsB + c * 16);
    }
    __syncthreads();
#pragma unroll
    for (int kk = 0; kk < 64; kk += 32) {
      const int j = (kk >> 3) + q;
      s8v af[4], bfr[4];
#pragma unroll
      for (int t = 0; t < 4; ++t) {
        af[t]  = *(const s8v*)((char*)lsA + (((wm + t * 16 + r) << 3) + (j ^ sw)) * 16);
        bfr[t] = *(const s8v*)((char*)lsB + (((wn + t * 16 + r) << 3) + (j ^ sw)) * 16);
      }
#pragma unroll
      for (int mi = 0; mi < 4; ++mi)
#pragma unroll
        for (int ni = 0; ni < 4; ++ni)
          acc[mi][ni] = __builtin_amdgcn_mfma_f32_16x16x32_bf16(af[mi], bfr[ni], acc[mi][ni], 0, 0, 0);
    }
    __syncthreads();
  }

#pragma unroll
  for (int mi = 0; mi < 4; ++mi)
#pragma unroll
    for (int j = 0; j < 4; ++j) {
      int row = m0 + wm + mi * 16 + q * 4 + j;
#pragma unroll
      for (int ni = 0; ni < 4; ++ni)
        epi_store<EPI>(acc[mi][ni][j], row, n0 + wn + ni * 16 + r, N, bias, resid, outH, outH2, outF);
    }
}

// ---------------- LayerNorm over D=1024, bf16 in -> bf16 out ----------------
__global__ __launch_bounds__(256) void ln_k(const bf16* __restrict__ y,
                                            const float* __restrict__ g,
                                            const float* __restrict__ b,
                                            bf16* __restrict__ out)
{
  __shared__ float sm[8];
  int row = blockIdx.x;
  bh4 v4 = ((const bh4*)(y + (size_t)row * D_))[threadIdx.x];
  float v0 = b2f(v4.h[0]), v1 = b2f(v4.h[1]), v2 = b2f(v4.h[2]), v3 = b2f(v4.h[3]);
  float s = v0 + v1 + v2 + v3;
#pragma unroll
  for (int o = 32; o; o >>= 1) s += __shfl_down(s, o);
  int lane = threadIdx.x & 63, w = threadIdx.x >> 6;
  if (lane == 0) sm[w] = s;
  __syncthreads();
  float mu = (sm[0] + sm[1] + sm[2] + sm[3]) * (1.f / D_);
  float d0 = v0 - mu, d1 = v1 - mu, d2 = v2 - mu, d3 = v3 - mu;
  float qq = d0 * d0 + d1 * d1 + d2 * d2 + d3 * d3;
#pragma unroll
  for (int o = 32; o; o >>= 1) qq += __shfl_down(qq, o);
  if (lane == 0) sm[4 + w] = qq;
  __syncthreads();
  float var = (sm[4] + sm[5] + sm[6] + sm[7]) * (1.f / D_);
  float inv = rsqrtf(var + 1e-5f);
  int c = threadIdx.x * 4;
  float4 gv = *(const float4*)(g + c);
  float4 bv = *(const float4*)(b + c);
  bh4 ov;
  ov.h[0] = f2b(d0 * inv * gv.x + bv.x);
  ov.h[1] = f2b(d1 * inv * gv.y + bv.y);
  ov.h[2] = f2b(d2 * inv * gv.z + bv.z);
  ov.h[3] = f2b(d3 * inv * gv.w + bv.w);
  *(bh4*)(out + (size_t)row * D_ + c) = ov;
}

// ---------------- chunked linear-recurrence scan, vec8: h' = sigmoid(fpre)*h + g ----------------
// Thread owns 8 contiguous e-columns of one chunk: 16B loads, 8 independent recurrences
// (ILP), 16 steps/chunk. Layout of Fc/Gc/hst: [c][be].
__global__ __launch_bounds__(256) void scanA2_k(const bf16* __restrict__ fpre,
                                                const bf16* __restrict__ g,
                                                float* __restrict__ Fc, float* __restrict__ Gc)
{
  int t = blockIdx.x * 256 + threadIdx.x;       // 0 .. NCH*BE_/8-1
  int c = t / (BE_ / 8);
  int col = t % (BE_ / 8);
  int be8 = col * 8;
  int b = be8 / E_, e = be8 % E_;
  size_t idx = (size_t)b * S_ * E_ + (size_t)c * CHS * E_ + e;
  float F[8], G[8];
#pragma unroll
  for (int j = 0; j < 8; ++j) { F[j] = 1.f; G[j] = 0.f; }
  for (int sl = 0; sl < CHS; ++sl, idx += E_) {
    s8v fv8 = *(const s8v*)(fpre + idx);
    s8v gv8 = *(const s8v*)(g + idx);
#pragma unroll
    for (int j = 0; j < 8; ++j) {
      float fv = 1.f / (1.f + expf(-su2f(fv8[j])));
      F[j] *= fv;
      G[j] = fv * G[j] + su2f(gv8[j]);
    }
  }
  size_t o = (size_t)c * BE_ + be8;
  *(float4*)(Fc + o)     = make_float4(F[0], F[1], F[2], F[3]);
  *(float4*)(Fc + o + 4) = make_float4(F[4], F[5], F[6], F[7]);
  *(float4*)(Gc + o)     = make_float4(G[0], G[1], G[2], G[3]);
  *(float4*)(Gc + o + 4) = make_float4(G[4], G[5], G[6], G[7]);
}

__global__ __launch_bounds__(256) void scanB_k(const float* __restrict__ Fc,
                                               const float* __restrict__ Gc,
                                               float* __restrict__ hst)
{
  int be = blockIdx.x * 256 + threadIdx.x;
  float h = 0.5f;
#pragma unroll 16
  for (int c = 0; c < NCH; ++c) {
    hst[c * BE_ + be] = h;
    h = Fc[c * BE_ + be] * h + Gc[c * BE_ + be];
  }
}

__global__ __launch_bounds__(256) void scanC2_k(const bf16* __restrict__ fpre,
                                                bf16* g,
                                                const float* __restrict__ hst)
{
  int t = blockIdx.x * 256 + threadIdx.x;
  int c = t / (BE_ / 8);
  int col = t % (BE_ / 8);
  int be8 = col * 8;
  int b = be8 / E_, e = be8 % E_;
  size_t idx = (size_t)b * S_ * E_ + (size_t)c * CHS * E_ + e;
  size_t o = (size_t)c * BE_ + be8;
  float4 h0 = *(const float4*)(hst + o);
  float4 h1 = *(const float4*)(hst + o + 4);
  float h[8] = {h0.x, h0.y, h0.z, h0.w, h1.x, h1.y, h1.z, h1.w};
  for (int sl = 0; sl < CHS; ++sl, idx += E_) {
    s8v fv8 = *(const s8v*)(fpre + idx);
    s8v gv8 = *(const s8v*)(g + idx);
    bh8 ov;
#pragma unroll
    for (int j = 0; j < 8; ++j) {
      float fv = 1.f / (1.f + expf(-su2f(fv8[j])));
      h[j] = fv * h[j] + su2f(gv8[j]);
      ov.h[j] = f2b(h[j]);
    }
    *(bh8*)(g + idx) = ov;
  }
}

extern "C" void kernel_launch(void* const* d_in, const int* in_sizes, int n_in,
                              void* d_out, int out_size, void* d_ws, size_t ws_size,
                              hipStream_t stream)
{
  (void)in_sizes; (void)n_in; (void)out_size; (void)ws_size;
  const float* x      = (const float*)d_in[0];
  const float* cdw_w  = (const float*)d_in[1];
  const float* cdw_b  = (const float*)d_in[2];
  const float* cpw_w  = (const float*)d_in[3];
  const float* cpw_b  = (const float*)d_in[4];
  const float* ln1_g  = (const float*)d_in[5];
  const float* ln1_b  = (const float*)d_in[6];
  const float* w_f    = (const float*)d_in[7];
  const float* w_i    = (const float*)d_in[8];
  const float* w_h    = (const float*)d_in[9];
  const float* w_down = (const float*)d_in[10];
  const float* ln2_g  = (const float*)d_in[11];
  const float* ln2_b  = (const float*)d_in[12];
  const float* mlp_w1 = (const float*)d_in[13];
  const float* mlp_b1 = (const float*)d_in[14];
  const float* mlp_w2 = (const float*)d_in[15];
  const float* mlp_b2 = (const float*)d_in[16];
  char* ws = (char*)d_ws;
  float* outF = (float*)d_out;

  // [0,16M)   dw_buf(conv) / xln(ln outputs); Fc/Gc/hst @[0,9.4M) during scans (xln dead)
  // [16,32M)  yb ; [16,80M) hmid (over yb/fpre/gvals, dead by then)
  // [32,58M)  fpre raw bf16 ; [58,80M) ipre raw -> g (RMW) -> h in-place
  // [80,110M) bf16 weights: pw | wfi | wh | wd | w1 | w2
  bf16* dw_buf = (bf16*)(ws + 0);
  bf16* xln    = (bf16*)(ws + 0);
  float* Fc    = (float*)(ws + 0);          // 128*6144*4 = 3,145,728
  float* Gc    = (float*)(ws + 3145728);
  float* hst   = (float*)(ws + 6291456);    // ends 9,437,184 < 16M
  bf16* yb     = (bf16*)(ws + 16777216);
  bf16* hmid   = (bf16*)(ws + 16777216);
  bf16* fpre   = (bf16*)(ws + 33554432);
  bf16* gvals  = (bf16*)(ws + 58720256);
  bf16* pwb    = (bf16*)(ws + 83886080);
  bf16* wfib   = (bf16*)(ws + 85983232);
  bf16* whb    = (bf16*)(ws + 92274688);
  bf16* wdb    = (bf16*)(ws + 95420416);
  bf16* w1b    = (bf16*)(ws + 98566144);
  bf16* w2b    = (bf16*)(ws + 106954752);

  cvt7_k<<<15360, 256, 0, stream>>>(cpw_w, w_f, w_i, w_h, w_down, mlp_w1, mlp_w2, pwb);

  dwconv_k<<<M_/TS_, 256, 0, stream>>>(x, cdw_w, cdw_b, dw_buf);
  gemm_ab<0><<<dim3(8, 64), 256, 0, stream>>>(dw_buf, D_, pwb, D_, cpw_b, x, yb, nullptr, nullptr, M_, D_, D_);
  ln_k<<<M_, 256, 0, stream>>>(yb, ln1_g, ln1_b, xln);
  // fused f+i raw pre-activations (N=3072), then h RMW: g = gh(v)*sigmoid(ipre)
  gemm_ab<1><<<dim3(24, 64), 256, 0, stream>>>(xln, D_, wfib, D_, nullptr, nullptr, fpre, gvals, nullptr, M_, 3072, D_);
  gemm_ab<2><<<dim3(12, 64), 256, 0, stream>>>(xln, D_, whb, D_, nullptr, nullptr, gvals, nullptr, nullptr, M_, E_, D_);
  scanA2_k<<<(NCH*BE_/8)/256, 256, 0, stream>>>(fpre, gvals, Fc, Gc);
  scanB_k<<<BE_/256, 256, 0, stream>>>(Fc, Gc, hst);
  scanC2_k<<<(NCH*BE_/8)/256, 256, 0, stream>>>(fpre, gvals, hst);
  gemm_ab<3><<<dim3(8, 64), 256, 0, stream>>>(gvals, E_, wdb, E_, nullptr, x, yb, nullptr, nullptr, M_, D_, E_);
  ln_k<<<M_, 256, 0, stream>>>(yb, ln2_g, ln2_b, xln);
  // fused MLP: one N=4096 GEMM -> hmid, one K=4096 GEMM -> d_out (fp32, single write)
  gemm_ab<4><<<dim3(32, 64), 256, 0, stream>>>(xln, D_, w1b, D_, mlp_b1, nullptr, hmid, nullptr, nullptr, M_, 4*D_, D_);
  gemm_ab<5><<<dim3(8, 64), 256, 0, stream>>>(hmid, 4*D_, w2b, 4*D_, mlp_b2, nullptr, nullptr, nullptr, outF, M_, D_, 4*D_);
}

// Round 5
// 599.037 us; speedup vs baseline: 1.4441x; 1.0418x over previous
//
#include <hip/hip_runtime.h>
#include <hip/hip_bf16.h>
#include <math.h>

using bf16 = __hip_bfloat16;
typedef __attribute__((ext_vector_type(8))) short s8v;   // 8 x bf16 raw (4 VGPRs)
typedef __attribute__((ext_vector_type(4))) float f32x4;

#define B_  4
#define S_  2048
#define D_  1024
#define E_  1536
#define M_  (B_*S_)     // 8192 tokens
#define BE_ (B_*E_)     // 6144 sequences
#define NCH 128         // scan chunks (vec8 scan: 384 blocks, 16 steps/chunk)
#define CHS (S_/NCH)    // 16 steps per chunk
#define TS_ 16          // dwconv tokens per block
#define DWB (M_/TS_)    // 512 dwconv blocks

__device__ __forceinline__ float b2f(bf16 h) { return __bfloat162float(h); }
__device__ __forceinline__ bf16  f2b(float f) { return __float2bfloat16(f); }
__device__ __forceinline__ float su2f(short v) {        // raw bf16 bits -> f32 (exact)
  unsigned u = ((unsigned)(unsigned short)v) << 16;
  return __builtin_bit_cast(float, u);
}

struct __align__(8)  bh4 { bf16 h[4]; };
struct __align__(16) bh8 { bf16 h[8]; };

__device__ __forceinline__ void gld16(const void* g, void* l) {
  __builtin_amdgcn_global_load_lds((const __attribute__((address_space(1))) void*)g,
                                   (__attribute__((address_space(3))) void*)l, 16, 0, 0);
}

// ---------------- fused prep: dwconv (blocks 0..511) + fp32->bf16 weight cvt (rest) ----------------
__global__ __launch_bounds__(256) void prep_k(const float* __restrict__ x,
                                              const float* __restrict__ cw,
                                              const float* __restrict__ cb,
                                              bf16* __restrict__ dw_out,
                                              const float* __restrict__ s0,
                                              const float* __restrict__ s1,
                                              const float* __restrict__ s2,
                                              const float* __restrict__ s3,
                                              const float* __restrict__ s4,
                                              const float* __restrict__ s5,
                                              const float* __restrict__ s6,
                                              bf16* __restrict__ wdst)
{
  if (blockIdx.x < DWB) {
    // depthwise causal conv (K=4), 16 tokens/block, read amp 1.19x
    int m0 = blockIdx.x * TS_;
    int sr0 = m0 & (S_ - 1);
    int d = threadIdx.x * 4;
    float wf[4][4];
#pragma unroll
    for (int i = 0; i < 4; ++i) {
      float4 wr = *(const float4*)(cw + (d + i) * 4);
      wf[i][0] = wr.x; wf[i][1] = wr.y; wf[i][2] = wr.z; wf[i][3] = wr.w;
    }
    float4 bb = *(const float4*)(cb + d);
    float4 xr[TS_ + 3];
#pragma unroll
    for (int j = 0; j < TS_ + 3; ++j) {
      int srow = sr0 - 3 + j;
      if (srow >= 0) xr[j] = *(const float4*)(x + (size_t)(m0 - 3 + j) * D_ + d);
      else           xr[j] = make_float4(0.f, 0.f, 0.f, 0.f);
    }
#pragma unroll
    for (int t = 0; t < TS_; ++t) {
      float a0 = bb.x, a1 = bb.y, a2 = bb.z, a3 = bb.w;
#pragma unroll
      for (int k = 0; k < 4; ++k) {
        float4 xv = xr[t + k];
        a0 += xv.x * wf[0][k];
        a1 += xv.y * wf[1][k];
        a2 += xv.z * wf[2][k];
        a3 += xv.w * wf[3][k];
      }
      bh4 ov;
      ov.h[0] = f2b(a0); ov.h[1] = f2b(a1); ov.h[2] = f2b(a2); ov.h[3] = f2b(a3);
      *(bh4*)(dw_out + (size_t)(m0 + t) * D_ + d) = ov;
    }
  } else {
    // weight conversion: contiguous dst pw | w_f | w_i | w_h | w_down | mlp_w1 | mlp_w2
    size_t i = ((size_t)(blockIdx.x - DWB) * 256 + threadIdx.x) * 4;
    const float* s; size_t off;
    if (i < 4194304) {
      if (i < 1048576)      { s = s0; off = 0; }
      else if (i < 2621440) { s = s1; off = 1048576; }
      else                  { s = s2; off = 2621440; }
    } else if (i < 7340032) {
      if (i < 5767168)      { s = s3; off = 4194304; }
      else                  { s = s4; off = 5767168; }
    } else {
      if (i < 11534336)     { s = s5; off = 7340032; }
      else                  { s = s6; off = 11534336; }
    }
    float4 v = *(const float4*)(s + (i - off));
    bh4 o;
    o.h[0] = f2b(v.x); o.h[1] = f2b(v.y); o.h[2] = f2b(v.z); o.h[3] = f2b(v.w);
    *(bh4*)(wdst + i) = o;
  }
}

// ---------------- shared epilogue ----------------
template<int EPI>
__device__ __forceinline__ void epi_store(float v, int row, int col, int N,
                                          const float* __restrict__ bias,
                                          const float* __restrict__ resid,
                                          bf16* outH, bf16* outH2, float* outF)
{
  size_t idx = (size_t)row * N + col;
  if constexpr (EPI == 0) {
    outH[idx] = f2b(v + bias[col] + resid[idx]);
  } else if constexpr (EPI == 1) {
    if (col < 1536) outH [(size_t)row * 1536 + col]        = f2b(v);
    else            outH2[(size_t)row * 1536 + col - 1536] = f2b(v);
  } else if constexpr (EPI == 2) {
    float gh = (v >= 0.f) ? (v + 0.5f) : (1.f / (1.f + expf(-v)));
    float iv = 1.f / (1.f + expf(-b2f(outH[idx])));
    outH[idx] = f2b(gh * iv);
  } else if constexpr (EPI == 3) {
    outH[idx] = f2b(v + resid[idx]);
  } else if constexpr (EPI == 4) {
    float u = v + bias[col];
    outH[idx] = f2b(0.5f * u * (1.f + erff(u * 0.70710678118f)));
  } else {
    outF[idx] = v + bias[col];
  }
}

// ======== GEMM 128x128 (proven): C(M,N)=A(M,K,lda)*B^T(N,K,ldb), bf16, swizzled LDS ========
// Sync structure frozen (stage-all -> sync -> 32 MFMA -> sync; TLP hides the drain, m114).
// R5 additions: (1) XCD-aware bijective blockIdx swizzle (T1): XCD k gets a contiguous
// chunk of logical tiles -> A/B panels reused within one L2 instead of 8 incoherent ones.
// Requires nwg%8==0 (all our grids: 512/768/1536/2048). (2) Pointer-bump staging: the 8
// per-thread global addresses are computed once and bumped by 64 elems/K-tile, removing
// the per-iter 64-bit address chains (m98: 21 v_lshl_add_u64/iter -> VALUBusy 63%).
template<int EPI>
__global__ __launch_bounds__(256) void gemm_ab(const bf16* __restrict__ A, int lda,
                                               const bf16* __restrict__ Bb, int ldb,
                                               const float* __restrict__ bias,
                                               const float* __restrict__ resid,
                                               bf16* outH, bf16* outH2, float* outF,
                                               int M, int N, int K)
{
  __shared__ __align__(16) bf16 lsA[128 * 64];
  __shared__ __align__(16) bf16 lsB[128 * 64];
  const int tid  = threadIdx.x;
  const int lane = tid & 63;
  const int wave = tid >> 6;
  // XCD swizzle: bid%8 == XCD id (HW round-robin); give XCD k contiguous tiles [k*cpx,(k+1)*cpx)
  const int gx  = gridDim.x;
  const int nwg = gx * gridDim.y;
  const int bid = blockIdx.y * gx + blockIdx.x;
  const int swz = (bid & 7) * (nwg >> 3) + (bid >> 3);
  const int m0 = (swz / gx) * 128, n0 = (swz % gx) * 128;
  const int wm = (wave >> 1) * 64, wn = (wave & 1) * 64;
  const int r = lane & 15, q = lane >> 4;
  const int sw = r & 7;
  f32x4 acc[4][4] = {};

  // hoisted per-thread staging addresses (bumped by 64 elems per K-tile)
  const bf16* pa[4]; const bf16* pb[4]; int dst[4];
#pragma unroll
  for (int i = 0; i < 4; ++i) {
    int c = i * 256 + tid;                     // LDS chunk id 0..1023
    int row = c >> 3, cc = (c & 7) ^ (row & 7);
    pa[i] = A  + (size_t)(m0 + row) * lda + cc * 8;
    pb[i] = Bb + (size_t)(n0 + row) * ldb + cc * 8;
    dst[i] = c * 16;
  }

  for (int k0 = 0; k0 < K; k0 += 64) {
#pragma unroll
    for (int i = 0; i < 4; ++i) {
      gld16(pa[i], (char*)lsA + dst[i]);
      gld16(pb[i], (char*)lsB + dst[i]);
      pa[i] += 64; pb[i] += 64;
    }
    __syncthreads();
#pragma unroll
    for (int kk = 0; kk < 64; kk += 32) {
      const int j = (kk >> 3) + q;
      s8v af[4], bfr[4];
#pragma unroll
      for (int t = 0; t < 4; ++t) {
        af[t]  = *(const s8v*)((char*)lsA + (((wm + t * 16 + r) << 3) + (j ^ sw)) * 16);
        bfr[t] = *(const s8v*)((char*)lsB + (((wn + t * 16 + r) << 3) + (j ^ sw)) * 16);
      }
#pragma unroll
      for (int mi = 0; mi < 4; ++mi)
#pragma unroll
        for (int ni = 0; ni < 4; ++ni)
          acc[mi][ni] = __builtin_amdgcn_mfma_f32_16x16x32_bf16(af[mi], bfr[ni], acc[mi][ni], 0, 0, 0);
    }
    __syncthreads();
  }

#pragma unroll
  for (int mi = 0; mi < 4; ++mi)
#pragma unroll
    for (int j = 0; j < 4; ++j) {
      int row = m0 + wm + mi * 16 + q * 4 + j;
#pragma unroll
      for (int ni = 0; ni < 4; ++ni)
        epi_store<EPI>(acc[mi][ni][j], row, n0 + wn + ni * 16 + r, N, bias, resid, outH, outH2, outF);
    }
}

// ---------------- LayerNorm over D=1024, bf16 in -> bf16 out ----------------
__global__ __launch_bounds__(256) void ln_k(const bf16* __restrict__ y,
                                            const float* __restrict__ g,
                                            const float* __restrict__ b,
                                            bf16* __restrict__ out)
{
  __shared__ float sm[8];
  int row = blockIdx.x;
  bh4 v4 = ((const bh4*)(y + (size_t)row * D_))[threadIdx.x];
  float v0 = b2f(v4.h[0]), v1 = b2f(v4.h[1]), v2 = b2f(v4.h[2]), v3 = b2f(v4.h[3]);
  float s = v0 + v1 + v2 + v3;
#pragma unroll
  for (int o = 32; o; o >>= 1) s += __shfl_down(s, o);
  int lane = threadIdx.x & 63, w = threadIdx.x >> 6;
  if (lane == 0) sm[w] = s;
  __syncthreads();
  float mu = (sm[0] + sm[1] + sm[2] + sm[3]) * (1.f / D_);
  float d0 = v0 - mu, d1 = v1 - mu, d2 = v2 - mu, d3 = v3 - mu;
  float qq = d0 * d0 + d1 * d1 + d2 * d2 + d3 * d3;
#pragma unroll
  for (int o = 32; o; o >>= 1) qq += __shfl_down(qq, o);
  if (lane == 0) sm[4 + w] = qq;
  __syncthreads();
  float var = (sm[4] + sm[5] + sm[6] + sm[7]) * (1.f / D_);
  float inv = rsqrtf(var + 1e-5f);
  int c = threadIdx.x * 4;
  float4 gv = *(const float4*)(g + c);
  float4 bv = *(const float4*)(b + c);
  bh4 ov;
  ov.h[0] = f2b(d0 * inv * gv.x + bv.x);
  ov.h[1] = f2b(d1 * inv * gv.y + bv.y);
  ov.h[2] = f2b(d2 * inv * gv.z + bv.z);
  ov.h[3] = f2b(d3 * inv * gv.w + bv.w);
  *(bh4*)(out + (size_t)row * D_ + c) = ov;
}

// ---------------- chunked linear-recurrence scan, vec8: h' = sigmoid(fpre)*h + g ----------------
__global__ __launch_bounds__(256) void scanA2_k(const bf16* __restrict__ fpre,
                                                const bf16* __restrict__ g,
                                                float* __restrict__ Fc, float* __restrict__ Gc)
{
  int t = blockIdx.x * 256 + threadIdx.x;       // 0 .. NCH*BE_/8-1
  int c = t / (BE_ / 8);
  int col = t % (BE_ / 8);
  int be8 = col * 8;
  int b = be8 / E_, e = be8 % E_;
  size_t idx = (size_t)b * S_ * E_ + (size_t)c * CHS * E_ + e;
  float F[8], G[8];
#pragma unroll
  for (int j = 0; j < 8; ++j) { F[j] = 1.f; G[j] = 0.f; }
  for (int sl = 0; sl < CHS; ++sl, idx += E_) {
    s8v fv8 = *(const s8v*)(fpre + idx);
    s8v gv8 = *(const s8v*)(g + idx);
#pragma unroll
    for (int j = 0; j < 8; ++j) {
      float fv = 1.f / (1.f + expf(-su2f(fv8[j])));
      F[j] *= fv;
      G[j] = fv * G[j] + su2f(gv8[j]);
    }
  }
  size_t o = (size_t)c * BE_ + be8;
  *(float4*)(Fc + o)     = make_float4(F[0], F[1], F[2], F[3]);
  *(float4*)(Fc + o + 4) = make_float4(F[4], F[5], F[6], F[7]);
  *(float4*)(Gc + o)     = make_float4(G[0], G[1], G[2], G[3]);
  *(float4*)(Gc + o + 4) = make_float4(G[4], G[5], G[6], G[7]);
}

__global__ __launch_bounds__(256) void scanB_k(const float* __restrict__ Fc,
                                               const float* __restrict__ Gc,
                                               float* __restrict__ hst)
{
  int be = blockIdx.x * 256 + threadIdx.x;
  float h = 0.5f;
#pragma unroll 16
  for (int c = 0; c < NCH; ++c) {
    hst[c * BE_ + be] = h;
    h = Fc[c * BE_ + be] * h + Gc[c * BE_ + be];
  }
}

__global__ __launch_bounds__(256) void scanC2_k(const bf16* __restrict__ fpre,
                                                bf16* g,
                                                const float* __restrict__ hst)
{
  int t = blockIdx.x * 256 + threadIdx.x;
  int c = t / (BE_ / 8);
  int col = t % (BE_ / 8);
  int be8 = col * 8;
  int b = be8 / E_, e = be8 % E_;
  size_t idx = (size_t)b * S_ * E_ + (size_t)c * CHS * E_ + e;
  size_t o = (size_t)c * BE_ + be8;
  float4 h0 = *(const float4*)(hst + o);
  float4 h1 = *(const float4*)(hst + o + 4);
  float h[8] = {h0.x, h0.y, h0.z, h0.w, h1.x, h1.y, h1.z, h1.w};
  for (int sl = 0; sl < CHS; ++sl, idx += E_) {
    s8v fv8 = *(const s8v*)(fpre + idx);
    s8v gv8 = *(const s8v*)(g + idx);
    bh8 ov;
#pragma unroll
    for (int j = 0; j < 8; ++j) {
      float fv = 1.f / (1.f + expf(-su2f(fv8[j])));
      h[j] = fv * h[j] + su2f(gv8[j]);
      ov.h[j] = f2b(h[j]);
    }
    *(bh8*)(g + idx) = ov;
  }
}

extern "C" void kernel_launch(void* const* d_in, const int* in_sizes, int n_in,
                              void* d_out, int out_size, void* d_ws, size_t ws_size,
                              hipStream_t stream)
{
  (void)in_sizes; (void)n_in; (void)out_size; (void)ws_size;
  const float* x      = (const float*)d_in[0];
  const float* cdw_w  = (const float*)d_in[1];
  const float* cdw_b  = (const float*)d_in[2];
  const float* cpw_w  = (const float*)d_in[3];
  const float* cpw_b  = (const float*)d_in[4];
  const float* ln1_g  = (const float*)d_in[5];
  const float* ln1_b  = (const float*)d_in[6];
  const float* w_f    = (const float*)d_in[7];
  const float* w_i    = (const float*)d_in[8];
  const float* w_h    = (const float*)d_in[9];
  const float* w_down = (const float*)d_in[10];
  const float* ln2_g  = (const float*)d_in[11];
  const float* ln2_b  = (const float*)d_in[12];
  const float* mlp_w1 = (const float*)d_in[13];
  const float* mlp_b1 = (const float*)d_in[14];
  const float* mlp_w2 = (const float*)d_in[15];
  const float* mlp_b2 = (const float*)d_in[16];
  char* ws = (char*)d_ws;
  float* outF = (float*)d_out;

  // [0,16M)   dw_buf(conv) / xln(ln outputs); Fc/Gc/hst @[0,9.4M) during scans (xln dead)
  // [16,32M)  yb ; [16,80M) hmid (over yb/fpre/gvals, dead by then)
  // [32,58M)  fpre raw bf16 ; [58,80M) ipre raw -> g (RMW) -> h in-place
  // [80,110M) bf16 weights: pw | wfi | wh | wd | w1 | w2
  bf16* dw_buf = (bf16*)(ws + 0);
  bf16* xln    = (bf16*)(ws + 0);
  float* Fc    = (float*)(ws + 0);          // 128*6144*4 = 3,145,728
  float* Gc    = (float*)(ws + 3145728);
  float* hst   = (float*)(ws + 6291456);    // ends 9,437,184 < 16M
  bf16* yb     = (bf16*)(ws + 16777216);
  bf16* hmid   = (bf16*)(ws + 16777216);
  bf16* fpre   = (bf16*)(ws + 33554432);
  bf16* gvals  = (bf16*)(ws + 58720256);
  bf16* pwb    = (bf16*)(ws + 83886080);
  bf16* wfib   = (bf16*)(ws + 85983232);
  bf16* whb    = (bf16*)(ws + 92274688);
  bf16* wdb    = (bf16*)(ws + 95420416);
  bf16* w1b    = (bf16*)(ws + 98566144);
  bf16* w2b    = (bf16*)(ws + 106954752);

  // fused: dwconv (512 blocks) + weight cvt (15360 blocks)
  prep_k<<<DWB + 15360, 256, 0, stream>>>(x, cdw_w, cdw_b, dw_buf,
                                          cpw_w, w_f, w_i, w_h, w_down, mlp_w1, mlp_w2, pwb);

  gemm_ab<0><<<dim3(8, 64), 256, 0, stream>>>(dw_buf, D_, pwb, D_, cpw_b, x, yb, nullptr, nullptr, M_, D_, D_);
  ln_k<<<M_, 256, 0, stream>>>(yb, ln1_g, ln1_b, xln);
  // fused f+i raw pre-activations (N=3072), then h RMW: g = gh(v)*sigmoid(ipre)
  gemm_ab<1><<<dim3(24, 64), 256, 0, stream>>>(xln, D_, wfib, D_, nullptr, nullptr, fpre, gvals, nullptr, M_, 3072, D_);
  gemm_ab<2><<<dim3(12, 64), 256, 0, stream>>>(xln, D_, whb, D_, nullptr, nullptr, gvals, nullptr, nullptr, M_, E_, D_);
  scanA2_k<<<(NCH*BE_/8)/256, 256, 0, stream>>>(fpre, gvals, Fc, Gc);
  scanB_k<<<BE_/256, 256, 0, stream>>>(Fc, Gc, hst);
  scanC2_k<<<(NCH*BE_/8)/256, 256, 0, stream>>>(fpre, gvals, hst);
  gemm_ab<3><<<dim3(8, 64), 256, 0, stream>>>(gvals, E_, wdb, E_, nullptr, x, yb, nullptr, nullptr, M_, D_, E_);
  ln_k<<<M_, 256, 0, stream>>>(yb, ln2_g, ln2_b, xln);
  // fused MLP: one N=4096 GEMM -> hmid, one K=4096 GEMM -> d_out (fp32, single write)
  gemm_ab<4><<<dim3(32, 64), 256, 0, stream>>>(xln, D_, w1b, D_, mlp_b1, nullptr, hmid, nullptr, nullptr, M_, 4*D_, D_);
  gemm_ab<5><<<dim3(8, 64), 256, 0, stream>>>(hmid, 4*D_, w2b, 4*D_, mlp_b2, nullptr, nullptr, nullptr, outF, M_, D_, 4*D_);
}